// Round 1
// baseline (775.161 us; speedup 1.0000x reference)
//
#include <hip/hip_runtime.h>
#include <hip/hip_bf16.h>
#include <math.h>

#define CT 2596      // total functor count C
#define NF36 36
#define BB 32        // batch
#define NN 32        // seq len
#define VV 32000
#define DD 64
#define NEGF -1e9f

__device__ __forceinline__ void lse_acc(float& m, float& s, float v) {
  float nm = fmaxf(m, v);
  s = s * __expf(m - nm) + __expf(v - nm);
  m = nm;
}
__device__ __forceinline__ void lse_join(float& m, float& s, float m2, float s2) {
  float nm = fmaxf(m, m2);
  s = s * __expf(m - nm) + s2 * __expf(m2 - nm);
  m = nm;
}

// ---------------------------------------------------------------------------
// K1: MLP over all C rows -> split0[c], split1[c]
// block = 256 = 4 rows x 64 threads
__global__ __launch_bounds__(256) void k_mlp(
    const float* __restrict__ nt_emb,
    const float* __restrict__ sW1, const float* __restrict__ sb1,
    const float* __restrict__ r1W1, const float* __restrict__ r1b1,
    const float* __restrict__ r1W2, const float* __restrict__ r1b2,
    const float* __restrict__ r2W1, const float* __restrict__ r2b1,
    const float* __restrict__ r2W2, const float* __restrict__ r2b2,
    const float* __restrict__ sW2, const float* __restrict__ sb2,
    float* __restrict__ split0, float* __restrict__ split1) {
  int tid = threadIdx.x;
  int rl = tid >> 6, j = tid & 63;
  int c = blockIdx.x * 4 + rl;
  __shared__ float hs[4][64], ts[4][64];

  ts[rl][j] = nt_emb[(size_t)c * 64 + j];
  __syncthreads();
  float a = sb1[j];
  for (int i = 0; i < 64; i++) a += ts[rl][i] * sW1[i * 64 + j];
  __syncthreads();
  hs[rl][j] = a;                       // h = nt_emb @ sW1 + sb1
  __syncthreads();
  // residual layer 1
  float u = r1b1[j];
  for (int i = 0; i < 64; i++) u += hs[rl][i] * r1W1[i * 64 + j];
  u = fmaxf(u, 0.f);
  ts[rl][j] = u;
  __syncthreads();
  float w = r1b2[j];
  for (int i = 0; i < 64; i++) w += ts[rl][i] * r1W2[i * 64 + j];
  w = fmaxf(w, 0.f) + hs[rl][j];
  __syncthreads();
  hs[rl][j] = w;
  __syncthreads();
  // residual layer 2
  u = r2b1[j];
  for (int i = 0; i < 64; i++) u += hs[rl][i] * r2W1[i * 64 + j];
  u = fmaxf(u, 0.f);
  ts[rl][j] = u;
  __syncthreads();
  w = r2b2[j];
  for (int i = 0; i < 64; i++) w += ts[rl][i] * r2W2[i * 64 + j];
  w = fmaxf(w, 0.f) + hs[rl][j];
  __syncthreads();
  hs[rl][j] = w;
  __syncthreads();
  // split = log_softmax(h @ sW2 + sb2) over 2
  if (j < 2) {
    float o = sb2[j];
    for (int i = 0; i < 64; i++) o += hs[rl][i] * sW2[i * 2 + j];
    ts[rl][j] = o;
  }
  __syncthreads();
  if (j < 2) {
    float o0 = ts[rl][0], o1 = ts[rl][1];
    float mx = fmaxf(o0, o1);
    float l = mx + __logf(__expf(o0 - mx) + __expf(o1 - mx));
    if (j == 0) split0[c] = o0 - l;
    else        split1[c] = o1 - l;
  }
}

// ---------------------------------------------------------------------------
// K2: rule log_softmax + root scores + G tables (needs split0)
__global__ __launch_bounds__(256) void k_prelim(
    const float* __restrict__ rule_W, const float* __restrict__ rule_b,
    const float* __restrict__ root_W, const float* __restrict__ root_b,
    const float* __restrict__ split0,
    float* __restrict__ Gl, float* __restrict__ Gr, float* __restrict__ root36) {
  __shared__ float rs[36 * 72];
  __shared__ float lse4s;
  int tid = threadIdx.x;
  if (tid < 36) {
    float mx = -1e30f;
    for (int q = 0; q < 72; q++) mx = fmaxf(mx, rule_W[tid * 72 + q] + rule_b[q]);
    float ss = 0.f;
    for (int q = 0; q < 72; q++) ss += __expf(rule_W[tid * 72 + q] + rule_b[q] - mx);
    float l = mx + __logf(ss);
    for (int q = 0; q < 72; q++) rs[tid * 72 + q] = rule_W[tid * 72 + q] + rule_b[q] - l;
  }
  if (tid == 0) {
    // masked entries (>=P) underflow to 0 in exp, so lse over first 4 only
    float mx = -1e30f;
    for (int i = 0; i < 4; i++) mx = fmaxf(mx, root_W[i] + root_b[i]);
    float ss = 0.f;
    for (int i = 0; i < 4; i++) ss += __expf(root_W[i] + root_b[i] - mx);
    lse4s = mx + __logf(ss);
  }
  __syncthreads();
  if (tid < 36)
    root36[tid] = ((tid < 4) ? 0.f : NEGF) + root_W[tid] + root_b[tid] - lse4s;
  for (int i = tid; i < 1296; i += 256) {
    int arg = i / 36, res = i - arg * 36;
    float s0 = split0[res];
    Gl[i] = rs[res * 72 + arg] + s0;        // Gl[arg,res] = rule[res,arg]+split0[res]
    Gr[i] = rs[res * 72 + 36 + arg] + s0;   // Gr[arg,res] = rule[res,36+arg]+split0[res]
  }
}

// ---------------------------------------------------------------------------
// K3: partial logsumexp over V per row (grid: 163 rowblocks x 8 v-slices)
__global__ __launch_bounds__(256) void k_lse_part(
    const float* __restrict__ nt_emb, const float* __restrict__ vocab_W,
    const float* __restrict__ vocab_b,
    float* __restrict__ partm, float* __restrict__ parts) {
  __shared__ float nt[16][64];
  __shared__ float redm[256][17];
  __shared__ float reds[256][17];
  int tid = threadIdx.x;
  int c0 = blockIdx.x * 16;
  int nr = min(16, CT - c0);
  for (int i = tid; i < 1024; i += 256) {
    int r = i >> 6, d = i & 63;
    nt[r][d] = (r < nr) ? nt_emb[(size_t)(c0 + r) * 64 + d] : 0.f;
  }
  __syncthreads();
  float m[16], s[16];
#pragma unroll
  for (int r = 0; r < 16; r++) { m[r] = -1e30f; s[r] = 0.f; }
  int vbase = blockIdx.y * 4000;
  int vend = vbase + 4000;
  for (int base = vbase; base < vend; base += 1024) {
    float acc[4][16];
#pragma unroll
    for (int u = 0; u < 4; u++)
#pragma unroll
      for (int r = 0; r < 16; r++) acc[u][r] = 0.f;
    int vv[4]; bool val[4];
#pragma unroll
    for (int u = 0; u < 4; u++) { vv[u] = base + (u << 8) + tid; val[u] = vv[u] < vend; }
#pragma unroll 2
    for (int d = 0; d < 64; d++) {
      float vw[4];
#pragma unroll
      for (int u = 0; u < 4; u++) vw[u] = val[u] ? vocab_W[(size_t)d * VV + vv[u]] : 0.f;
#pragma unroll
      for (int r = 0; r < 16; r++) {
        float nv = nt[r][d];
#pragma unroll
        for (int u = 0; u < 4; u++) acc[u][r] = fmaf(nv, vw[u], acc[u][r]);
      }
    }
#pragma unroll
    for (int u = 0; u < 4; u++) if (val[u]) {
      float vb = vocab_b[vv[u]];
#pragma unroll
      for (int r = 0; r < 16; r++) lse_acc(m[r], s[r], acc[u][r] + vb);
    }
  }
#pragma unroll
  for (int r = 0; r < 16; r++) { redm[tid][r] = m[r]; reds[tid][r] = s[r]; }
  __syncthreads();
  for (int step = 128; step > 0; step >>= 1) {
    if (tid < step) {
#pragma unroll
      for (int r = 0; r < 16; r++)
        lse_join(redm[tid][r], reds[tid][r], redm[tid + step][r], reds[tid + step][r]);
    }
    __syncthreads();
  }
  if (tid < nr) {
    partm[(size_t)blockIdx.y * CT + c0 + tid] = redm[0][tid];
    parts[(size_t)blockIdx.y * CT + c0 + tid] = reds[0][tid];
  }
}

// K4: combine the 8 v-slices -> lse[c]
__global__ void k_lse_combine(const float* __restrict__ partm,
                              const float* __restrict__ parts,
                              float* __restrict__ lse) {
  int c = blockIdx.x * 256 + threadIdx.x;
  if (c >= CT) return;
  float m = -1e30f, s = 0.f;
  for (int vs = 0; vs < 8; vs++)
    lse_join(m, s, partm[(size_t)vs * CT + c], parts[(size_t)vs * CT + c]);
  lse[c] = m + __logf(s);
}

// ---------------------------------------------------------------------------
// K5: beta1[n,b,c] = logit(c, x[b,n]) - lse[c] + split1[c]
__global__ __launch_bounds__(256) void k_beta1(
    const float* __restrict__ nt_emb, const float* __restrict__ vocab_W,
    const float* __restrict__ vocab_b, const int* __restrict__ x,
    const float* __restrict__ lse, const float* __restrict__ split1,
    float* __restrict__ beta1) {
  __shared__ float nt[16][64];
  __shared__ float lseS[16], sp1S[16];
  int tid = threadIdx.x;
  int c0 = blockIdx.x * 16;
  int nr = min(16, CT - c0);
  for (int i = tid; i < 1024; i += 256) {
    int r = i >> 6, d = i & 63;
    nt[r][d] = (r < nr) ? nt_emb[(size_t)(c0 + r) * 64 + d] : 0.f;
  }
  if (tid < 16) {
    lseS[tid] = (tid < nr) ? lse[c0 + tid] : 0.f;
    sp1S[tid] = (tid < nr) ? split1[c0 + tid] : 0.f;
  }
  __syncthreads();
  for (int j = tid; j < BB * NN; j += 256) {
    int tok = x[j];
    float acc[16];
#pragma unroll
    for (int r = 0; r < 16; r++) acc[r] = 0.f;
#pragma unroll 4
    for (int d = 0; d < 64; d++) {
      float vw = vocab_W[(size_t)d * VV + tok];
#pragma unroll
      for (int r = 0; r < 16; r++) acc[r] = fmaf(nt[r][d], vw, acc[r]);
    }
    float vb = vocab_b[tok];
    int b = j >> 5, np = j & 31;                 // x is (B,N) row-major
    size_t basei = ((size_t)(np * 32 + b)) * CT + c0;
    for (int r = 0; r < nr; r++)
      beta1[basei + r] = acc[r] + vb - lseS[r] + sp1S[r];
  }
}

// ---------------------------------------------------------------------------
// K6: gathered edge tables with G folded in.
// lf1G[(s*32+b)*1296 + arg*36+res] = beta1[s,b, lf[arg,res]] + Gr[arg,res]
// rf1G[...]                        = beta1[s,b, rf[arg,res]] + Gl[arg,res]
__global__ __launch_bounds__(256) void k_edge(
    const float* __restrict__ beta1, const int* __restrict__ lf_t,
    const int* __restrict__ rf_t, const float* __restrict__ Gl,
    const float* __restrict__ Gr,
    float* __restrict__ lf1G, float* __restrict__ rf1G) {
  int sb = blockIdx.x;
  const float* brow = beta1 + (size_t)sb * CT;
  size_t ob = (size_t)sb * 1296;
  for (int i = threadIdx.x; i < 1296; i += 256) {
    lf1G[ob + i] = brow[lf_t[i]] + Gr[i];
    rf1G[ob + i] = brow[rf_t[i]] + Gl[i];
  }
}

// ---------------------------------------------------------------------------
// K7: CKY inside pass. One block per batch element; chart lives in LDS.
// Key fact: valid masks restrict non-length-1-child branches to res<4 && arg<4.
__global__ __launch_bounds__(1024) void k_cky(
    const float* __restrict__ beta1, const float* __restrict__ lf1G,
    const float* __restrict__ rf1G, const float* __restrict__ Gl,
    const float* __restrict__ Gr, const float* __restrict__ root36,
    float* __restrict__ out) {
  __shared__ float chart[19008];      // sum_{L=1..32} (33-L)*36
  __shared__ float GlS[1296], GrS[1296], rootS[36];
  int b = blockIdx.x, tid = threadIdx.x;
  for (int i = tid; i < 1296; i += 1024) { GlS[i] = Gl[i]; GrS[i] = Gr[i]; }
  if (tid < 36) rootS[tid] = root36[tid];
  for (int i = tid; i < 32 * 36; i += 1024) {
    int s = i / 36, res = i - s * 36;
    chart[i] = beta1[(size_t)(s * 32 + b) * CT + res];   // level 1 = beta1[:, :, :36]
  }
  __syncthreads();
  for (int L = 2; L <= 32; L++) {
    int S = 33 - L;
    int offL   = 36 * (((L - 1) * (66 - L)) >> 1);
    int offLm1 = 36 * (((L - 2) * (67 - L)) >> 1);
    int tot = S * 36;
    for (int o = tid; o < tot; o += 1024) {
      int s = o / 36, res = o - s * 36;
      float m0 = -1e30f, s0 = 0.f, m1 = -1e30f, s1 = 0.f;
      const float* c1s   = chart + s * 36;                 // chart[1][s]
      const float* lprev = chart + offLm1 + s * 36;        // chart[L-1][s]
      const float* rprev = chart + offLm1 + (s + 1) * 36;  // chart[L-1][s+1]
      // k=1, branch B (full): right[arg] + beta1-gather(lf) + Gr
      const float* lg = lf1G + (size_t)(s * 32 + b) * 1296 + res;
#pragma unroll
      for (int a = 0; a < 36; a += 2) {
        lse_acc(m0, s0, rprev[a]     + lg[a * 36]);
        lse_acc(m1, s1, rprev[a + 1] + lg[(a + 1) * 36]);
      }
      if (L == 2) {
        // k=1 is also k=L-1: branch A full via rf1G[s+1]
        const float* rg = rf1G + (size_t)((s + 1) * 32 + b) * 1296 + res;
#pragma unroll
        for (int a = 0; a < 36; a += 2) {
          lse_acc(m0, s0, c1s[a]     + rg[a * 36]);
          lse_acc(m1, s1, c1s[a + 1] + rg[(a + 1) * 36]);
        }
      } else {
        const float* c1e = chart + (s + L - 1) * 36;       // chart[1][s+L-1]
        // k=L-1, branch A (full): left[arg] + beta1-gather(rf) + Gl
        const float* rg = rf1G + (size_t)((s + L - 1) * 32 + b) * 1296 + res;
#pragma unroll
        for (int a = 0; a < 36; a += 2) {
          lse_acc(m0, s0, lprev[a]     + rg[a * 36]);
          lse_acc(m1, s1, lprev[a + 1] + rg[(a + 1) * 36]);
        }
        if (res < 4) {
          // k=1 branch A corner; k=L-1 branch B corner
#pragma unroll
          for (int a = 0; a < 4; a++) {
            lse_acc(m0, s0, c1s[a] + rprev[20 + res * 4 + a] + GlS[a * 36 + res]);
            lse_acc(m1, s1, c1e[a] + lprev[4 + res * 4 + a]  + GrS[a * 36 + res]);
          }
          // middle splits: both children length>=2 -> 4x4 corner only
          for (int k = 2; k <= L - 2; k++) {
            const float* lv = chart + 36 * (((k - 1) * (66 - k)) >> 1) + s * 36;
            const float* rv = chart + 36 * (((L - k - 1) * (66 - (L - k))) >> 1) + (s + k) * 36;
#pragma unroll
            for (int a = 0; a < 4; a++) {
              lse_acc(m0, s0, lv[a] + rv[20 + res * 4 + a] + GlS[a * 36 + res]);
              lse_acc(m1, s1, rv[a] + lv[4 + res * 4 + a]  + GrS[a * 36 + res]);
            }
          }
        }
      }
      lse_join(m0, s0, m1, s1);
      chart[offL + o] = m0 + __logf(s0);
    }
    __syncthreads();
  }
  if (tid == 0) {
    int off32 = 36 * ((31 * 34) >> 1);
    float m = -1e30f, s = 0.f;
    for (int r = 0; r < 36; r++) lse_acc(m, s, chart[off32 + r] + rootS[r]);
    out[b] = -(m + __logf(s));
  }
}

// ---------------------------------------------------------------------------
extern "C" void kernel_launch(void* const* d_in, const int* in_sizes, int n_in,
                              void* d_out, int out_size, void* d_ws, size_t ws_size,
                              hipStream_t stream) {
  const int*   x       = (const int*)d_in[0];
  const int*   lf_t    = (const int*)d_in[1];
  const int*   rf_t    = (const int*)d_in[2];
  const float* root_W  = (const float*)d_in[3];
  const float* root_b  = (const float*)d_in[4];
  const float* rule_W  = (const float*)d_in[5];
  const float* rule_b  = (const float*)d_in[6];
  const float* nt_emb  = (const float*)d_in[7];
  const float* sW1     = (const float*)d_in[8];
  const float* sb1     = (const float*)d_in[9];
  const float* r1W1    = (const float*)d_in[10];
  const float* r1b1    = (const float*)d_in[11];
  const float* r1W2    = (const float*)d_in[12];
  const float* r1b2    = (const float*)d_in[13];
  const float* r2W1    = (const float*)d_in[14];
  const float* r2b1    = (const float*)d_in[15];
  const float* r2W2    = (const float*)d_in[16];
  const float* r2b2    = (const float*)d_in[17];
  const float* sW2     = (const float*)d_in[18];
  const float* sb2     = (const float*)d_in[19];
  const float* vocab_W = (const float*)d_in[20];
  const float* vocab_b = (const float*)d_in[21];
  float* outp = (float*)d_out;

  float* ws = (float*)d_ws;
  float* split0 = ws;                    // 2596
  float* split1 = ws + 2596;             // 2596
  float* Gl     = ws + 5192;             // 1296
  float* Gr     = ws + 6488;             // 1296
  float* root36 = ws + 7784;             // 36 (pad to 7824)
  float* lse    = ws + 7824;             // 2596
  float* partm  = ws + 10420;            // 8*2596 = 20768
  float* parts  = ws + 31188;            // 20768
  float* beta1  = ws + 51956;            // 32*32*2596 = 2658304
  float* lf1G   = ws + 2710260;          // 32*32*1296 = 1327104
  float* rf1G   = ws + 4037364;          // 1327104  (total 5364468 floats ~= 20.5 MiB)

  k_mlp<<<649, 256, 0, stream>>>(nt_emb, sW1, sb1, r1W1, r1b1, r1W2, r1b2,
                                 r2W1, r2b1, r2W2, r2b2, sW2, sb2, split0, split1);
  k_prelim<<<1, 256, 0, stream>>>(rule_W, rule_b, root_W, root_b, split0, Gl, Gr, root36);
  k_lse_part<<<dim3(163, 8), 256, 0, stream>>>(nt_emb, vocab_W, vocab_b, partm, parts);
  k_lse_combine<<<11, 256, 0, stream>>>(partm, parts, lse);
  k_beta1<<<163, 256, 0, stream>>>(nt_emb, vocab_W, vocab_b, x, lse, split1, beta1);
  k_edge<<<1024, 256, 0, stream>>>(beta1, lf_t, rf_t, Gl, Gr, lf1G, rf1G);
  k_cky<<<32, 1024, 0, stream>>>(beta1, lf1G, rf1G, Gl, Gr, root36, outp);
}

// Round 2
// 520.174 us; speedup vs baseline: 1.4902x; 1.4902x over previous
//
#include <hip/hip_runtime.h>
#include <hip/hip_bf16.h>
#include <math.h>

#define CT 2596      // total functor count C
#define NF36 36
#define BB 32        // batch
#define NN 32        // seq len
#define VV 32000
#define DD 64
#define NEGF -1e9f

__device__ __forceinline__ void lse_acc(float& m, float& s, float v) {
  float nm = fmaxf(m, v);
  s = s * __expf(m - nm) + __expf(v - nm);
  m = nm;
}
__device__ __forceinline__ void lse_join(float& m, float& s, float m2, float s2) {
  float nm = fmaxf(m, m2);
  s = s * __expf(m - nm) + s2 * __expf(m2 - nm);
  m = nm;
}

// bf16 helpers (no API dependence)
__device__ __forceinline__ uint32_t f2bf_bits(float x) {
  union { float f; uint32_t u; } v; v.f = x;
  return (v.u + 0x7FFFu + ((v.u >> 16) & 1u)) >> 16;   // RNE
}
__device__ __forceinline__ float bflo(uint32_t u) {
  union { uint32_t u; float f; } v; v.u = u << 16; return v.f;
}
__device__ __forceinline__ float bfhi(uint32_t u) {
  union { uint32_t u; float f; } v; v.u = u & 0xFFFF0000u; return v.f;
}

// ---------------------------------------------------------------------------
// K1: MLP over all C rows -> split0[c], split1[c]
__global__ __launch_bounds__(256) void k_mlp(
    const float* __restrict__ nt_emb,
    const float* __restrict__ sW1, const float* __restrict__ sb1,
    const float* __restrict__ r1W1, const float* __restrict__ r1b1,
    const float* __restrict__ r1W2, const float* __restrict__ r1b2,
    const float* __restrict__ r2W1, const float* __restrict__ r2b1,
    const float* __restrict__ r2W2, const float* __restrict__ r2b2,
    const float* __restrict__ sW2, const float* __restrict__ sb2,
    float* __restrict__ split0, float* __restrict__ split1) {
  int tid = threadIdx.x;
  int rl = tid >> 6, j = tid & 63;
  int c = blockIdx.x * 4 + rl;
  __shared__ float hs[4][64], ts[4][64];

  ts[rl][j] = nt_emb[(size_t)c * 64 + j];
  __syncthreads();
  float a = sb1[j];
  for (int i = 0; i < 64; i++) a += ts[rl][i] * sW1[i * 64 + j];
  __syncthreads();
  hs[rl][j] = a;
  __syncthreads();
  float u = r1b1[j];
  for (int i = 0; i < 64; i++) u += hs[rl][i] * r1W1[i * 64 + j];
  u = fmaxf(u, 0.f);
  ts[rl][j] = u;
  __syncthreads();
  float w = r1b2[j];
  for (int i = 0; i < 64; i++) w += ts[rl][i] * r1W2[i * 64 + j];
  w = fmaxf(w, 0.f) + hs[rl][j];
  __syncthreads();
  hs[rl][j] = w;
  __syncthreads();
  u = r2b1[j];
  for (int i = 0; i < 64; i++) u += hs[rl][i] * r2W1[i * 64 + j];
  u = fmaxf(u, 0.f);
  ts[rl][j] = u;
  __syncthreads();
  w = r2b2[j];
  for (int i = 0; i < 64; i++) w += ts[rl][i] * r2W2[i * 64 + j];
  w = fmaxf(w, 0.f) + hs[rl][j];
  __syncthreads();
  hs[rl][j] = w;
  __syncthreads();
  if (j < 2) {
    float o = sb2[j];
    for (int i = 0; i < 64; i++) o += hs[rl][i] * sW2[i * 2 + j];
    ts[rl][j] = o;
  }
  __syncthreads();
  if (j < 2) {
    float o0 = ts[rl][0], o1 = ts[rl][1];
    float mx = fmaxf(o0, o1);
    float l = mx + __logf(__expf(o0 - mx) + __expf(o1 - mx));
    if (j == 0) split0[c] = o0 - l;
    else        split1[c] = o1 - l;
  }
}

// ---------------------------------------------------------------------------
// K2: rule log_softmax + root scores + G tables (needs split0)
__global__ __launch_bounds__(256) void k_prelim(
    const float* __restrict__ rule_W, const float* __restrict__ rule_b,
    const float* __restrict__ root_W, const float* __restrict__ root_b,
    const float* __restrict__ split0,
    float* __restrict__ Gl, float* __restrict__ Gr, float* __restrict__ root36) {
  __shared__ float rs[36 * 72];
  __shared__ float lse4s;
  int tid = threadIdx.x;
  if (tid < 36) {
    float mx = -1e30f;
    for (int q = 0; q < 72; q++) mx = fmaxf(mx, rule_W[tid * 72 + q] + rule_b[q]);
    float ss = 0.f;
    for (int q = 0; q < 72; q++) ss += __expf(rule_W[tid * 72 + q] + rule_b[q] - mx);
    float l = mx + __logf(ss);
    for (int q = 0; q < 72; q++) rs[tid * 72 + q] = rule_W[tid * 72 + q] + rule_b[q] - l;
  }
  if (tid == 0) {
    float mx = -1e30f;
    for (int i = 0; i < 4; i++) mx = fmaxf(mx, root_W[i] + root_b[i]);
    float ss = 0.f;
    for (int i = 0; i < 4; i++) ss += __expf(root_W[i] + root_b[i] - mx);
    lse4s = mx + __logf(ss);
  }
  __syncthreads();
  if (tid < 36)
    root36[tid] = ((tid < 4) ? 0.f : NEGF) + root_W[tid] + root_b[tid] - lse4s;
  for (int i = tid; i < 1296; i += 256) {
    int arg = i / 36, res = i - arg * 36;
    float s0 = split0[res];
    Gl[i] = rs[res * 72 + arg] + s0;
    Gr[i] = rs[res * 72 + 36 + arg] + s0;
  }
}

// ---------------------------------------------------------------------------
// K3: partial logsumexp over V per row
__global__ __launch_bounds__(256) void k_lse_part(
    const float* __restrict__ nt_emb, const float* __restrict__ vocab_W,
    const float* __restrict__ vocab_b,
    float* __restrict__ partm, float* __restrict__ parts) {
  __shared__ float nt[16][64];
  __shared__ float redm[256][17];
  __shared__ float reds[256][17];
  int tid = threadIdx.x;
  int c0 = blockIdx.x * 16;
  int nr = min(16, CT - c0);
  for (int i = tid; i < 1024; i += 256) {
    int r = i >> 6, d = i & 63;
    nt[r][d] = (r < nr) ? nt_emb[(size_t)(c0 + r) * 64 + d] : 0.f;
  }
  __syncthreads();
  float m[16], s[16];
#pragma unroll
  for (int r = 0; r < 16; r++) { m[r] = -1e30f; s[r] = 0.f; }
  int vbase = blockIdx.y * 4000;
  int vend = vbase + 4000;
  for (int base = vbase; base < vend; base += 1024) {
    float acc[4][16];
#pragma unroll
    for (int u = 0; u < 4; u++)
#pragma unroll
      for (int r = 0; r < 16; r++) acc[u][r] = 0.f;
    int vv[4]; bool val[4];
#pragma unroll
    for (int u = 0; u < 4; u++) { vv[u] = base + (u << 8) + tid; val[u] = vv[u] < vend; }
#pragma unroll 2
    for (int d = 0; d < 64; d++) {
      float vw[4];
#pragma unroll
      for (int u = 0; u < 4; u++) vw[u] = val[u] ? vocab_W[(size_t)d * VV + vv[u]] : 0.f;
#pragma unroll
      for (int r = 0; r < 16; r++) {
        float nv = nt[r][d];
#pragma unroll
        for (int u = 0; u < 4; u++) acc[u][r] = fmaf(nv, vw[u], acc[u][r]);
      }
    }
#pragma unroll
    for (int u = 0; u < 4; u++) if (val[u]) {
      float vb = vocab_b[vv[u]];
#pragma unroll
      for (int r = 0; r < 16; r++) lse_acc(m[r], s[r], acc[u][r] + vb);
    }
  }
#pragma unroll
  for (int r = 0; r < 16; r++) { redm[tid][r] = m[r]; reds[tid][r] = s[r]; }
  __syncthreads();
  for (int step = 128; step > 0; step >>= 1) {
    if (tid < step) {
#pragma unroll
      for (int r = 0; r < 16; r++)
        lse_join(redm[tid][r], reds[tid][r], redm[tid + step][r], reds[tid + step][r]);
    }
    __syncthreads();
  }
  if (tid < nr) {
    partm[(size_t)blockIdx.y * CT + c0 + tid] = redm[0][tid];
    parts[(size_t)blockIdx.y * CT + c0 + tid] = reds[0][tid];
  }
}

// K4: combine the 8 v-slices -> lse[c]
__global__ void k_lse_combine(const float* __restrict__ partm,
                              const float* __restrict__ parts,
                              float* __restrict__ lse) {
  int c = blockIdx.x * 256 + threadIdx.x;
  if (c >= CT) return;
  float m = -1e30f, s = 0.f;
  for (int vs = 0; vs < 8; vs++)
    lse_join(m, s, partm[(size_t)vs * CT + c], parts[(size_t)vs * CT + c]);
  lse[c] = m + __logf(s);
}

// ---------------------------------------------------------------------------
// K5: beta1[n,b,c] = logit(c, x[b,n]) - lse[c] + split1[c]
__global__ __launch_bounds__(256) void k_beta1(
    const float* __restrict__ nt_emb, const float* __restrict__ vocab_W,
    const float* __restrict__ vocab_b, const int* __restrict__ x,
    const float* __restrict__ lse, const float* __restrict__ split1,
    float* __restrict__ beta1) {
  __shared__ float nt[16][64];
  __shared__ float lseS[16], sp1S[16];
  int tid = threadIdx.x;
  int c0 = blockIdx.x * 16;
  int nr = min(16, CT - c0);
  for (int i = tid; i < 1024; i += 256) {
    int r = i >> 6, d = i & 63;
    nt[r][d] = (r < nr) ? nt_emb[(size_t)(c0 + r) * 64 + d] : 0.f;
  }
  if (tid < 16) {
    lseS[tid] = (tid < nr) ? lse[c0 + tid] : 0.f;
    sp1S[tid] = (tid < nr) ? split1[c0 + tid] : 0.f;
  }
  __syncthreads();
  for (int j = tid; j < BB * NN; j += 256) {
    int tok = x[j];
    float acc[16];
#pragma unroll
    for (int r = 0; r < 16; r++) acc[r] = 0.f;
#pragma unroll 4
    for (int d = 0; d < 64; d++) {
      float vw = vocab_W[(size_t)d * VV + tok];
#pragma unroll
      for (int r = 0; r < 16; r++) acc[r] = fmaf(nt[r][d], vw, acc[r]);
    }
    float vb = vocab_b[tok];
    int b = j >> 5, np = j & 31;
    size_t basei = ((size_t)(np * 32 + b)) * CT + c0;
    for (int r = 0; r < nr; r++)
      beta1[basei + r] = acc[r] + vb - lseS[r] + sp1S[r];
  }
}

// ---------------------------------------------------------------------------
// K6: EXP-space edge tables, bf16-pair packed.
// elp[sb*648 + p*36+res] packs exp(beta1[s,b,lf[2p,res]]+Gr[2p,res]) (lo)
//                           and exp(beta1[s,b,lf[2p+1,res]]+Gr[2p+1,res]) (hi)
// erp likewise with rf/Gl.
__global__ __launch_bounds__(256) void k_edge(
    const float* __restrict__ beta1, const int* __restrict__ lf_t,
    const int* __restrict__ rf_t, const float* __restrict__ Gl,
    const float* __restrict__ Gr,
    uint32_t* __restrict__ elp, uint32_t* __restrict__ erp) {
  int sb = blockIdx.x;
  const float* brow = beta1 + (size_t)sb * CT;
  size_t ob = (size_t)sb * 648;
  for (int j = threadIdx.x; j < 648; j += 256) {
    int p = j / 36, res = j - p * 36;
    int i0 = (2 * p) * 36 + res, i1 = i0 + 36;
    float e0 = __expf(brow[lf_t[i0]] + Gr[i0]);
    float e1 = __expf(brow[lf_t[i1]] + Gr[i1]);
    elp[ob + j] = f2bf_bits(e0) | (f2bf_bits(e1) << 16);
    e0 = __expf(brow[rf_t[i0]] + Gl[i0]);
    e1 = __expf(brow[rf_t[i1]] + Gl[i1]);
    erp[ob + j] = f2bf_bits(e0) | (f2bf_bits(e1) << 16);
  }
}

// ---------------------------------------------------------------------------
// K7: CKY inside pass, EXP-space. One block per batch element.
// Chart stored as D[L][s][j] = exp(chart[L][s][j] - M[L][s]), M in Mt.
__global__ __launch_bounds__(1024) void k_cky(
    const float* __restrict__ beta1, const uint32_t* __restrict__ elp,
    const uint32_t* __restrict__ erp, const float* __restrict__ Gl,
    const float* __restrict__ Gr, const float* __restrict__ root36,
    float* __restrict__ out) {
  __shared__ float D[19008];        // exp-chart
  __shared__ float Mt[528];         // per (L,s) scale
  __shared__ float PA[1116], PB[1116];
  __shared__ float cand[33];
  __shared__ float Ec1l[512], Ec1r[512];  // [s][a*4+res], a<4,res<4
  __shared__ float eGl16[16], eGr16[16];

  int b = blockIdx.x, tid = threadIdx.x;
  int wid = tid >> 6, lane = tid & 63;

  // init: level 1
  for (int i = tid; i < 32 * 36; i += 1024) {
    int s = i / 36, j = i - s * 36;
    D[i] = __expf(beta1[(size_t)(s * 32 + b) * CT + j]);
  }
  if (tid < 32) Mt[tid] = 0.f;
  if (tid < 16) {
    int a = tid >> 2, res = tid & 3;
    eGl16[tid] = __expf(Gl[a * 36 + res]);
    eGr16[tid] = __expf(Gr[a * 36 + res]);
  }
  __syncthreads();
  for (int i = tid; i < 512; i += 1024) {
    int s = i >> 4, q = i & 15;      // q = a*4+res
    float d1 = D[s * 36 + (q >> 2)];
    Ec1l[i] = d1 * eGl16[q];
    Ec1r[i] = d1 * eGr16[q];
  }
  __syncthreads();

  for (int L = 2; L <= 32; L++) {
    int S = 33 - L;
    int offL   = 36 * (((L - 1) * (66 - L)) >> 1);
    int offP   = 36 * (((L - 2) * (67 - L)) >> 1);
    int offML  = ((L - 1) * (66 - L)) >> 1;
    int offMP  = ((L - 2) * (67 - L)) >> 1;

    // phase 1a: cand[s'] = M[L-1][s'] + log(max_a D[L-1][s'][a])
    for (int sp = wid; sp <= S; sp += 16) {
      float v = (lane < 36) ? D[offP + sp * 36 + lane] : 0.f;
#pragma unroll
      for (int w = 32; w > 0; w >>= 1) v = fmaxf(v, __shfl_xor(v, w));
      v = fmaxf(v, 1e-37f);
      if (lane == 0) cand[sp] = Mt[offMP + sp] + __logf(v);
    }
    __syncthreads();
    // phase 1b: Mnew[s], P arrays
    for (int s = wid; s < S; s += 16) {
      float Mn = fmaxf(cand[s], cand[s + 1]);
      float fA = __expf(Mt[offMP + s] - Mn);
      float fB = __expf(Mt[offMP + s + 1] - Mn);
      if (lane < 36) {
        PA[s * 36 + lane] = D[offP + s * 36 + lane] * fA;
        PB[s * 36 + lane] = D[offP + (s + 1) * 36 + lane] * fB;
      }
      if (lane == 0) Mt[offML + s] = Mn;
    }
    __syncthreads();

    // phase 2: dot products
    int tot = S * 36;
    for (int o = tid; o < tot; o += 1024) {
      int s = o / 36, res = o - s * 36;
      const uint32_t* el = elp + (size_t)(s * 32 + b) * 648 + res;
      const uint32_t* er = erp + (size_t)((s + L - 1) * 32 + b) * 648 + res;
      const float* pB = PB + s * 36;
      const float* pA = PA + s * 36;
      float acc0 = 0.f, acc1 = 0.f;
#pragma unroll
      for (int p = 0; p < 18; p++) {
        uint32_t u = el[p * 36];
        acc0 = fmaf(pB[2 * p],     bflo(u), acc0);
        acc1 = fmaf(pB[2 * p + 1], bfhi(u), acc1);
        uint32_t w = er[p * 36];
        acc0 = fmaf(pA[2 * p],     bflo(w), acc0);
        acc1 = fmaf(pA[2 * p + 1], bfhi(w), acc1);
      }
      if (res < 4 && L >= 3) {
        float Mn = Mt[offML + s];
#pragma unroll
        for (int a = 0; a < 4; a++) {
          acc0 += Ec1l[s * 16 + a * 4 + res] * pB[20 + res * 4 + a];
          acc1 += Ec1r[(s + L - 1) * 16 + a * 4 + res] * pA[4 + res * 4 + a];
        }
        for (int k = 2; k <= L - 2; k++) {
          const float* dk = D + 36 * (((k - 1) * (66 - k)) >> 1) + s * 36;
          const float* dl = D + 36 * (((L - k - 1) * (66 - (L - k))) >> 1) + (s + k) * 36;
          float f = __expf(Mt[(((k - 1) * (66 - k)) >> 1) + s] +
                           Mt[(((L - k - 1) * (66 - (L - k))) >> 1) + s + k] - Mn);
          float sub = 0.f;
#pragma unroll
          for (int a = 0; a < 4; a++) {
            sub = fmaf(dk[a] * dl[20 + res * 4 + a], eGl16[a * 4 + res], sub);
            sub = fmaf(dl[a] * dk[4 + res * 4 + a],  eGr16[a * 4 + res], sub);
          }
          acc0 = fmaf(f, sub, acc0);
        }
      }
      D[offL + o] = acc0 + acc1;
    }
    __syncthreads();
  }

  // final: out[b] = -(M[32][0] + log(sum_r D[32][0][r] * exp(root36[r])))
  if (wid == 0) {
    int off32 = 36 * ((31 * 34) >> 1);
    float v = (lane < 36) ? D[off32 + lane] * __expf(root36[lane]) : 0.f;
#pragma unroll
    for (int w = 32; w > 0; w >>= 1) v += __shfl_xor(v, w);
    if (lane == 0) out[b] = -(Mt[527] + __logf(v));
  }
}

// ---------------------------------------------------------------------------
extern "C" void kernel_launch(void* const* d_in, const int* in_sizes, int n_in,
                              void* d_out, int out_size, void* d_ws, size_t ws_size,
                              hipStream_t stream) {
  const int*   x       = (const int*)d_in[0];
  const int*   lf_t    = (const int*)d_in[1];
  const int*   rf_t    = (const int*)d_in[2];
  const float* root_W  = (const float*)d_in[3];
  const float* root_b  = (const float*)d_in[4];
  const float* rule_W  = (const float*)d_in[5];
  const float* rule_b  = (const float*)d_in[6];
  const float* nt_emb  = (const float*)d_in[7];
  const float* sW1     = (const float*)d_in[8];
  const float* sb1     = (const float*)d_in[9];
  const float* r1W1    = (const float*)d_in[10];
  const float* r1b1    = (const float*)d_in[11];
  const float* r1W2    = (const float*)d_in[12];
  const float* r1b2    = (const float*)d_in[13];
  const float* r2W1    = (const float*)d_in[14];
  const float* r2b1    = (const float*)d_in[15];
  const float* r2W2    = (const float*)d_in[16];
  const float* r2b2    = (const float*)d_in[17];
  const float* sW2     = (const float*)d_in[18];
  const float* sb2     = (const float*)d_in[19];
  const float* vocab_W = (const float*)d_in[20];
  const float* vocab_b = (const float*)d_in[21];
  float* outp = (float*)d_out;

  float* ws = (float*)d_ws;
  float* split0 = ws;                    // 2596
  float* split1 = ws + 2596;             // 2596
  float* Gl     = ws + 5192;             // 1296
  float* Gr     = ws + 6488;             // 1296
  float* root36 = ws + 7784;             // 36 (pad to 7824)
  float* lse    = ws + 7824;             // 2596
  float* partm  = ws + 10420;            // 20768
  float* parts  = ws + 31188;            // 20768
  float* beta1  = ws + 51956;            // 32*32*2596 = 2658304
  uint32_t* elp = (uint32_t*)(ws + 2710260);  // 1024*648 u32
  uint32_t* erp = (uint32_t*)(ws + 3373812);  // 1024*648 u32 (end 4037364)

  k_mlp<<<649, 256, 0, stream>>>(nt_emb, sW1, sb1, r1W1, r1b1, r1W2, r1b2,
                                 r2W1, r2b1, r2W2, r2b2, sW2, sb2, split0, split1);
  k_prelim<<<1, 256, 0, stream>>>(rule_W, rule_b, root_W, root_b, split0, Gl, Gr, root36);
  k_lse_part<<<dim3(163, 8), 256, 0, stream>>>(nt_emb, vocab_W, vocab_b, partm, parts);
  k_lse_combine<<<11, 256, 0, stream>>>(partm, parts, lse);
  k_beta1<<<163, 256, 0, stream>>>(nt_emb, vocab_W, vocab_b, x, lse, split1, beta1);
  k_edge<<<1024, 256, 0, stream>>>(beta1, lf_t, rf_t, Gl, Gr, elp, erp);
  k_cky<<<32, 1024, 0, stream>>>(beta1, elp, erp, Gl, Gr, root36, outp);
}

// Round 3
// 318.704 us; speedup vs baseline: 2.4322x; 1.6322x over previous
//
#include <hip/hip_runtime.h>
#include <hip/hip_bf16.h>
#include <math.h>

#define CT 2596      // total functor count C
#define NF36 36
#define BB 32        // batch
#define NN 32        // seq len
#define VV 32000
#define DD 64
#define NEGF -1e9f
#define NVT 2000     // V tiles of 16

typedef __attribute__((ext_vector_type(8))) short bf16x8;
typedef __attribute__((ext_vector_type(4))) float f32x4;

__device__ __forceinline__ void lse_acc(float& m, float& s, float v) {
  float nm = fmaxf(m, v);
  s = s * __expf(m - nm) + __expf(v - nm);
  m = nm;
}

// bf16 helpers
__device__ __forceinline__ uint32_t f2bf_bits(float x) {
  union { float f; uint32_t u; } v; v.f = x;
  return (v.u + 0x7FFFu + ((v.u >> 16) & 1u)) >> 16;   // RNE
}
__device__ __forceinline__ float bflo(uint32_t u) {
  union { uint32_t u; float f; } v; v.u = u << 16; return v.f;
}
__device__ __forceinline__ float bfhi(uint32_t u) {
  union { uint32_t u; float f; } v; v.u = u & 0xFFFF0000u; return v.f;
}

// ---------------------------------------------------------------------------
// K1: MLP over all C rows -> split0[c], split1[c]
__global__ __launch_bounds__(256) void k_mlp(
    const float* __restrict__ nt_emb,
    const float* __restrict__ sW1, const float* __restrict__ sb1,
    const float* __restrict__ r1W1, const float* __restrict__ r1b1,
    const float* __restrict__ r1W2, const float* __restrict__ r1b2,
    const float* __restrict__ r2W1, const float* __restrict__ r2b1,
    const float* __restrict__ r2W2, const float* __restrict__ r2b2,
    const float* __restrict__ sW2, const float* __restrict__ sb2,
    float* __restrict__ split0, float* __restrict__ split1) {
  int tid = threadIdx.x;
  int rl = tid >> 6, j = tid & 63;
  int c = blockIdx.x * 4 + rl;
  __shared__ float hs[4][64], ts[4][64];

  ts[rl][j] = nt_emb[(size_t)c * 64 + j];
  __syncthreads();
  float a = sb1[j];
  for (int i = 0; i < 64; i++) a += ts[rl][i] * sW1[i * 64 + j];
  __syncthreads();
  hs[rl][j] = a;
  __syncthreads();
  float u = r1b1[j];
  for (int i = 0; i < 64; i++) u += hs[rl][i] * r1W1[i * 64 + j];
  u = fmaxf(u, 0.f);
  ts[rl][j] = u;
  __syncthreads();
  float w = r1b2[j];
  for (int i = 0; i < 64; i++) w += ts[rl][i] * r1W2[i * 64 + j];
  w = fmaxf(w, 0.f) + hs[rl][j];
  __syncthreads();
  hs[rl][j] = w;
  __syncthreads();
  u = r2b1[j];
  for (int i = 0; i < 64; i++) u += hs[rl][i] * r2W1[i * 64 + j];
  u = fmaxf(u, 0.f);
  ts[rl][j] = u;
  __syncthreads();
  w = r2b2[j];
  for (int i = 0; i < 64; i++) w += ts[rl][i] * r2W2[i * 64 + j];
  w = fmaxf(w, 0.f) + hs[rl][j];
  __syncthreads();
  hs[rl][j] = w;
  __syncthreads();
  if (j < 2) {
    float o = sb2[j];
    for (int i = 0; i < 64; i++) o += hs[rl][i] * sW2[i * 2 + j];
    ts[rl][j] = o;
  }
  __syncthreads();
  if (j < 2) {
    float o0 = ts[rl][0], o1 = ts[rl][1];
    float mx = fmaxf(o0, o1);
    float l = mx + __logf(__expf(o0 - mx) + __expf(o1 - mx));
    if (j == 0) split0[c] = o0 - l;
    else        split1[c] = o1 - l;
  }
}

// ---------------------------------------------------------------------------
// K2: rule log_softmax + root scores + G tables (needs split0)
__global__ __launch_bounds__(256) void k_prelim(
    const float* __restrict__ rule_W, const float* __restrict__ rule_b,
    const float* __restrict__ root_W, const float* __restrict__ root_b,
    const float* __restrict__ split0,
    float* __restrict__ Gl, float* __restrict__ Gr, float* __restrict__ root36) {
  __shared__ float rs[36 * 72];
  __shared__ float lse4s;
  int tid = threadIdx.x;
  if (tid < 36) {
    float mx = -1e30f;
    for (int q = 0; q < 72; q++) mx = fmaxf(mx, rule_W[tid * 72 + q] + rule_b[q]);
    float ss = 0.f;
    for (int q = 0; q < 72; q++) ss += __expf(rule_W[tid * 72 + q] + rule_b[q] - mx);
    float l = mx + __logf(ss);
    for (int q = 0; q < 72; q++) rs[tid * 72 + q] = rule_W[tid * 72 + q] + rule_b[q] - l;
  }
  if (tid == 0) {
    float mx = -1e30f;
    for (int i = 0; i < 4; i++) mx = fmaxf(mx, root_W[i] + root_b[i]);
    float ss = 0.f;
    for (int i = 0; i < 4; i++) ss += __expf(root_W[i] + root_b[i] - mx);
    lse4s = mx + __logf(ss);
  }
  __syncthreads();
  if (tid < 36)
    root36[tid] = ((tid < 4) ? 0.f : NEGF) + root_W[tid] + root_b[tid] - lse4s;
  for (int i = tid; i < 1296; i += 256) {
    int arg = i / 36, res = i - arg * 36;
    float s0 = split0[res];
    Gl[i] = rs[res * 72 + arg] + s0;
    Gr[i] = rs[res * 72 + 36 + arg] + s0;
  }
}

// ---------------------------------------------------------------------------
// K3a: repack vocab_W into bf16 MFMA B-fragments.
// Slot g = vt*128 + f*64 + l : uint4 holding k-pairs for lane l, frag f
// (col v = vt*16 + (l&15), k = f*32 + 8*(l>>4) + {0..7}).
__global__ __launch_bounds__(256) void k_cvt_w(
    const float* __restrict__ vocab_W, uint4* __restrict__ Wt) {
  int g = blockIdx.x * 256 + threadIdx.x;
  if (g >= NVT * 128) return;
  int l = g & 63;
  int f = (g >> 6) & 1;
  int vt = g >> 7;
  int v = vt * 16 + (l & 15);
  int kb = f * 32 + 8 * (l >> 4);
  uint32_t d[4];
#pragma unroll
  for (int p = 0; p < 4; p++) {
    float a = vocab_W[(size_t)(kb + 2 * p) * VV + v];
    float b = vocab_W[(size_t)(kb + 2 * p + 1) * VV + v];
    d[p] = f2bf_bits(a) | (f2bf_bits(b) << 16);
  }
  uint4 o; o.x = d[0]; o.y = d[1]; o.z = d[2]; o.w = d[3];
  Wt[g] = o;
}

// ---------------------------------------------------------------------------
// K3b: MFMA GEMM + fused exp-sum over V. Block = 4 waves, owns 64 C-rows.
// grid = (NV v-slices, 41 c-blocks). No max-shift: |logits| ~ O(6), fp32-safe.
__global__ __launch_bounds__(256) void k_lse_mfma(
    const float* __restrict__ nt_emb, const uint4* __restrict__ Wt,
    const float* __restrict__ vocab_b, float* __restrict__ lseacc) {
  int tid = threadIdx.x;
  int w = tid >> 6, l = tid & 63;
  int c0 = blockIdx.y * 64;
  int lrow = l & 15, lgrp = l >> 4;

  bf16x8 A[4][2];
#pragma unroll
  for (int ct = 0; ct < 4; ct++) {
    int row = c0 + ct * 16 + lrow;
#pragma unroll
    for (int kf = 0; kf < 2; kf++) {
      bf16x8 fr;
      if (row < CT) {
        const float4* src = (const float4*)(nt_emb + (size_t)row * 64 + kf * 32 + lgrp * 8);
        float4 s0 = src[0], s1 = src[1];
        fr[0] = (short)f2bf_bits(s0.x); fr[1] = (short)f2bf_bits(s0.y);
        fr[2] = (short)f2bf_bits(s0.z); fr[3] = (short)f2bf_bits(s0.w);
        fr[4] = (short)f2bf_bits(s1.x); fr[5] = (short)f2bf_bits(s1.y);
        fr[6] = (short)f2bf_bits(s1.z); fr[7] = (short)f2bf_bits(s1.w);
      } else {
#pragma unroll
        for (int e = 0; e < 8; e++) fr[e] = 0;
      }
      A[ct][kf] = fr;
    }
  }

  float sums[4][4];
#pragma unroll
  for (int ct = 0; ct < 4; ct++)
#pragma unroll
    for (int i = 0; i < 4; i++) sums[ct][i] = 0.f;

  int tend = (blockIdx.x + 1) * (NVT / 8);
  for (int t = blockIdx.x * (NVT / 8) + w; t < tend; t += 4) {
    union { uint4 u; bf16x8 h; } b0, b1;
    b0.u = Wt[(size_t)(t * 2) * 64 + l];
    b1.u = Wt[(size_t)(t * 2 + 1) * 64 + l];
    float vb = vocab_b[t * 16 + lrow];
#pragma unroll
    for (int ct = 0; ct < 4; ct++) {
      f32x4 acc = {0.f, 0.f, 0.f, 0.f};
      acc = __builtin_amdgcn_mfma_f32_16x16x32_bf16(A[ct][0], b0.h, acc, 0, 0, 0);
      acc = __builtin_amdgcn_mfma_f32_16x16x32_bf16(A[ct][1], b1.h, acc, 0, 0, 0);
#pragma unroll
      for (int i = 0; i < 4; i++) sums[ct][i] += __expf(acc[i] + vb);
    }
  }

  // reduce over the 16 lanes sharing a row (lane bits 0-3 = col)
#pragma unroll
  for (int ct = 0; ct < 4; ct++)
#pragma unroll
    for (int i = 0; i < 4; i++) {
      float v = sums[ct][i];
      v += __shfl_xor(v, 1);
      v += __shfl_xor(v, 2);
      v += __shfl_xor(v, 4);
      v += __shfl_xor(v, 8);
      sums[ct][i] = v;
    }
  if (lrow == 0) {
#pragma unroll
    for (int ct = 0; ct < 4; ct++)
#pragma unroll
      for (int i = 0; i < 4; i++) {
        int row = c0 + ct * 16 + lgrp * 4 + i;
        if (row < CT) atomicAdd(&lseacc[row], sums[ct][i]);
      }
  }
}

// K3c: lse[c] = log(sum)
__global__ void k_lse_final(const float* __restrict__ lseacc, float* __restrict__ lse) {
  int c = blockIdx.x * 256 + threadIdx.x;
  if (c < CT) lse[c] = __logf(lseacc[c]);
}

// ---------------------------------------------------------------------------
// K5: beta1[n,b,c] = logit(c, x[b,n]) - lse[c] + split1[c]
__global__ __launch_bounds__(256) void k_beta1(
    const float* __restrict__ nt_emb, const float* __restrict__ vocab_W,
    const float* __restrict__ vocab_b, const int* __restrict__ x,
    const float* __restrict__ lse, const float* __restrict__ split1,
    float* __restrict__ beta1) {
  __shared__ float nt[16][64];
  __shared__ float lseS[16], sp1S[16];
  int tid = threadIdx.x;
  int c0 = blockIdx.x * 16;
  int nr = min(16, CT - c0);
  for (int i = tid; i < 1024; i += 256) {
    int r = i >> 6, d = i & 63;
    nt[r][d] = (r < nr) ? nt_emb[(size_t)(c0 + r) * 64 + d] : 0.f;
  }
  if (tid < 16) {
    lseS[tid] = (tid < nr) ? lse[c0 + tid] : 0.f;
    sp1S[tid] = (tid < nr) ? split1[c0 + tid] : 0.f;
  }
  __syncthreads();
  for (int j = tid; j < BB * NN; j += 256) {
    int tok = x[j];
    float acc[16];
#pragma unroll
    for (int r = 0; r < 16; r++) acc[r] = 0.f;
#pragma unroll 4
    for (int d = 0; d < 64; d++) {
      float vw = vocab_W[(size_t)d * VV + tok];
#pragma unroll
      for (int r = 0; r < 16; r++) acc[r] = fmaf(nt[r][d], vw, acc[r]);
    }
    float vb = vocab_b[tok];
    int b = j >> 5, np = j & 31;
    size_t basei = ((size_t)(np * 32 + b)) * CT + c0;
    for (int r = 0; r < nr; r++)
      beta1[basei + r] = acc[r] + vb - lseS[r] + sp1S[r];
  }
}

// ---------------------------------------------------------------------------
// K6: EXP-space edge tables, bf16-pair packed.
__global__ __launch_bounds__(256) void k_edge(
    const float* __restrict__ beta1, const int* __restrict__ lf_t,
    const int* __restrict__ rf_t, const float* __restrict__ Gl,
    const float* __restrict__ Gr,
    uint32_t* __restrict__ elp, uint32_t* __restrict__ erp) {
  int sb = blockIdx.x;
  const float* brow = beta1 + (size_t)sb * CT;
  size_t ob = (size_t)sb * 648;
  for (int j = threadIdx.x; j < 648; j += 256) {
    int p = j / 36, res = j - p * 36;
    int i0 = (2 * p) * 36 + res, i1 = i0 + 36;
    float e0 = __expf(brow[lf_t[i0]] + Gr[i0]);
    float e1 = __expf(brow[lf_t[i1]] + Gr[i1]);
    elp[ob + j] = f2bf_bits(e0) | (f2bf_bits(e1) << 16);
    e0 = __expf(brow[rf_t[i0]] + Gl[i0]);
    e1 = __expf(brow[rf_t[i1]] + Gl[i1]);
    erp[ob + j] = f2bf_bits(e0) | (f2bf_bits(e1) << 16);
  }
}

// ---------------------------------------------------------------------------
// K7: CKY inside pass, EXP-space. One block per batch element.
__global__ __launch_bounds__(1024) void k_cky(
    const float* __restrict__ beta1, const uint32_t* __restrict__ elp,
    const uint32_t* __restrict__ erp, const float* __restrict__ Gl,
    const float* __restrict__ Gr, const float* __restrict__ root36,
    float* __restrict__ out) {
  __shared__ float D[19008];
  __shared__ float Mt[528];
  __shared__ float PA[1116], PB[1116];
  __shared__ float cand[33];
  __shared__ float Ec1l[512], Ec1r[512];
  __shared__ float eGl16[16], eGr16[16];

  int b = blockIdx.x, tid = threadIdx.x;
  int wid = tid >> 6, lane = tid & 63;

  for (int i = tid; i < 32 * 36; i += 1024) {
    int s = i / 36, j = i - s * 36;
    D[i] = __expf(beta1[(size_t)(s * 32 + b) * CT + j]);
  }
  if (tid < 32) Mt[tid] = 0.f;
  if (tid < 16) {
    int a = tid >> 2, res = tid & 3;
    eGl16[tid] = __expf(Gl[a * 36 + res]);
    eGr16[tid] = __expf(Gr[a * 36 + res]);
  }
  __syncthreads();
  for (int i = tid; i < 512; i += 1024) {
    int s = i >> 4, q = i & 15;
    float d1 = D[s * 36 + (q >> 2)];
    Ec1l[i] = d1 * eGl16[q];
    Ec1r[i] = d1 * eGr16[q];
  }
  __syncthreads();

  for (int L = 2; L <= 32; L++) {
    int S = 33 - L;
    int offL   = 36 * (((L - 1) * (66 - L)) >> 1);
    int offP   = 36 * (((L - 2) * (67 - L)) >> 1);
    int offML  = ((L - 1) * (66 - L)) >> 1;
    int offMP  = ((L - 2) * (67 - L)) >> 1;

    for (int sp = wid; sp <= S; sp += 16) {
      float v = (lane < 36) ? D[offP + sp * 36 + lane] : 0.f;
#pragma unroll
      for (int w = 32; w > 0; w >>= 1) v = fmaxf(v, __shfl_xor(v, w));
      v = fmaxf(v, 1e-37f);
      if (lane == 0) cand[sp] = Mt[offMP + sp] + __logf(v);
    }
    __syncthreads();
    for (int s = wid; s < S; s += 16) {
      float Mn = fmaxf(cand[s], cand[s + 1]);
      float fA = __expf(Mt[offMP + s] - Mn);
      float fB = __expf(Mt[offMP + s + 1] - Mn);
      if (lane < 36) {
        PA[s * 36 + lane] = D[offP + s * 36 + lane] * fA;
        PB[s * 36 + lane] = D[offP + (s + 1) * 36 + lane] * fB;
      }
      if (lane == 0) Mt[offML + s] = Mn;
    }
    __syncthreads();

    int tot = S * 36;
    for (int o = tid; o < tot; o += 1024) {
      int s = o / 36, res = o - s * 36;
      const uint32_t* el = elp + (size_t)(s * 32 + b) * 648 + res;
      const uint32_t* er = erp + (size_t)((s + L - 1) * 32 + b) * 648 + res;
      const float* pB = PB + s * 36;
      const float* pA = PA + s * 36;
      float acc0 = 0.f, acc1 = 0.f;
#pragma unroll
      for (int p = 0; p < 18; p++) {
        uint32_t u = el[p * 36];
        acc0 = fmaf(pB[2 * p],     bflo(u), acc0);
        acc1 = fmaf(pB[2 * p + 1], bfhi(u), acc1);
        uint32_t w = er[p * 36];
        acc0 = fmaf(pA[2 * p],     bflo(w), acc0);
        acc1 = fmaf(pA[2 * p + 1], bfhi(w), acc1);
      }
      if (res < 4 && L >= 3) {
        float Mn = Mt[offML + s];
#pragma unroll
        for (int a = 0; a < 4; a++) {
          acc0 += Ec1l[s * 16 + a * 4 + res] * pB[20 + res * 4 + a];
          acc1 += Ec1r[(s + L - 1) * 16 + a * 4 + res] * pA[4 + res * 4 + a];
        }
        for (int k = 2; k <= L - 2; k++) {
          const float* dk = D + 36 * (((k - 1) * (66 - k)) >> 1) + s * 36;
          const float* dl = D + 36 * (((L - k - 1) * (66 - (L - k))) >> 1) + (s + k) * 36;
          float f = __expf(Mt[(((k - 1) * (66 - k)) >> 1) + s] +
                           Mt[(((L - k - 1) * (66 - (L - k))) >> 1) + s + k] - Mn);
          float sub = 0.f;
#pragma unroll
          for (int a = 0; a < 4; a++) {
            sub = fmaf(dk[a] * dl[20 + res * 4 + a], eGl16[a * 4 + res], sub);
            sub = fmaf(dl[a] * dk[4 + res * 4 + a],  eGr16[a * 4 + res], sub);
          }
          acc0 = fmaf(f, sub, acc0);
        }
      }
      D[offL + o] = acc0 + acc1;
    }
    __syncthreads();
  }

  if (wid == 0) {
    int off32 = 36 * ((31 * 34) >> 1);
    float v = (lane < 36) ? D[off32 + lane] * __expf(root36[lane]) : 0.f;
#pragma unroll
    for (int w = 32; w > 0; w >>= 1) v += __shfl_xor(v, w);
    if (lane == 0) out[b] = -(Mt[527] + __logf(v));
  }
}

// ---------------------------------------------------------------------------
extern "C" void kernel_launch(void* const* d_in, const int* in_sizes, int n_in,
                              void* d_out, int out_size, void* d_ws, size_t ws_size,
                              hipStream_t stream) {
  const int*   x       = (const int*)d_in[0];
  const int*   lf_t    = (const int*)d_in[1];
  const int*   rf_t    = (const int*)d_in[2];
  const float* root_W  = (const float*)d_in[3];
  const float* root_b  = (const float*)d_in[4];
  const float* rule_W  = (const float*)d_in[5];
  const float* rule_b  = (const float*)d_in[6];
  const float* nt_emb  = (const float*)d_in[7];
  const float* sW1     = (const float*)d_in[8];
  const float* sb1     = (const float*)d_in[9];
  const float* r1W1    = (const float*)d_in[10];
  const float* r1b1    = (const float*)d_in[11];
  const float* r1W2    = (const float*)d_in[12];
  const float* r1b2    = (const float*)d_in[13];
  const float* r2W1    = (const float*)d_in[14];
  const float* r2b1    = (const float*)d_in[15];
  const float* r2W2    = (const float*)d_in[16];
  const float* r2b2    = (const float*)d_in[17];
  const float* sW2     = (const float*)d_in[18];
  const float* sb2     = (const float*)d_in[19];
  const float* vocab_W = (const float*)d_in[20];
  const float* vocab_b = (const float*)d_in[21];
  float* outp = (float*)d_out;

  float* ws = (float*)d_ws;
  float* split0 = ws;                         // 2596
  float* split1 = ws + 2596;                  // 2596
  float* Gl     = ws + 5192;                  // 1296
  float* Gr     = ws + 6488;                  // 1296
  float* root36 = ws + 7784;                  // 64 (pad)
  float* lse    = ws + 7848;                  // 2596
  float* lseacc = ws + 10444;                 // 2596 -> pad to 13040
  float* beta1  = ws + 13040;                 // 2658304 -> end 2671344
  uint32_t* elp = (uint32_t*)(ws + 2671344);  // 663552
  uint32_t* erp = (uint32_t*)(ws + 3334896);  // 663552 -> end 3998448
  uint4*    Wt  = (uint4*)(ws + 3998448);     // 256000 uint4 -> end 5022448 floats

  k_mlp<<<649, 256, 0, stream>>>(nt_emb, sW1, sb1, r1W1, r1b1, r1W2, r1b2,
                                 r2W1, r2b1, r2W2, r2b2, sW2, sb2, split0, split1);
  k_prelim<<<1, 256, 0, stream>>>(rule_W, rule_b, root_W, root_b, split0, Gl, Gr, root36);
  k_cvt_w<<<1000, 256, 0, stream>>>(vocab_W, Wt);
  hipMemsetAsync(lseacc, 0, CT * sizeof(float), stream);
  k_lse_mfma<<<dim3(8, 41), 256, 0, stream>>>(nt_emb, Wt, vocab_b, lseacc);
  k_lse_final<<<11, 256, 0, stream>>>(lseacc, lse);
  k_beta1<<<163, 256, 0, stream>>>(nt_emb, vocab_W, vocab_b, x, lse, split1, beta1);
  k_edge<<<1024, 256, 0, stream>>>(beta1, lf_t, rf_t, Gl, Gr, elp, erp);
  k_cky<<<32, 1024, 0, stream>>>(beta1, elp, erp, Gl, Gr, root36, outp);
}

// Round 4
// 288.568 us; speedup vs baseline: 2.6862x; 1.1044x over previous
//
#include <hip/hip_runtime.h>
#include <hip/hip_bf16.h>
#include <math.h>

#define CT 2596      // total functor count C
#define NF36 36
#define BB 32        // batch
#define NN 32        // seq len
#define VV 32000
#define DD 64
#define NEGF -1e9f
#define NVT 2000     // V tiles of 16

typedef __attribute__((ext_vector_type(8))) short bf16x8;
typedef __attribute__((ext_vector_type(4))) float f32x4;

__device__ __forceinline__ void lse_acc(float& m, float& s, float v) {
  float nm = fmaxf(m, v);
  s = s * __expf(m - nm) + __expf(v - nm);
  m = nm;
}

// bf16 helpers
__device__ __forceinline__ uint32_t f2bf_bits(float x) {
  union { float f; uint32_t u; } v; v.f = x;
  return (v.u + 0x7FFFu + ((v.u >> 16) & 1u)) >> 16;   // RNE
}
__device__ __forceinline__ float bflo(uint32_t u) {
  union { uint32_t u; float f; } v; v.u = u << 16; return v.f;
}
__device__ __forceinline__ float bfhi(uint32_t u) {
  union { uint32_t u; float f; } v; v.u = u & 0xFFFF0000u; return v.f;
}

// ---------------------------------------------------------------------------
// K1: MLP over all C rows -> split0[c], split1[c]
__global__ __launch_bounds__(256) void k_mlp(
    const float* __restrict__ nt_emb,
    const float* __restrict__ sW1, const float* __restrict__ sb1,
    const float* __restrict__ r1W1, const float* __restrict__ r1b1,
    const float* __restrict__ r1W2, const float* __restrict__ r1b2,
    const float* __restrict__ r2W1, const float* __restrict__ r2b1,
    const float* __restrict__ r2W2, const float* __restrict__ r2b2,
    const float* __restrict__ sW2, const float* __restrict__ sb2,
    float* __restrict__ split0, float* __restrict__ split1) {
  int tid = threadIdx.x;
  int rl = tid >> 6, j = tid & 63;
  int c = blockIdx.x * 4 + rl;
  __shared__ float hs[4][64], ts[4][64];

  ts[rl][j] = nt_emb[(size_t)c * 64 + j];
  __syncthreads();
  float a = sb1[j];
  for (int i = 0; i < 64; i++) a += ts[rl][i] * sW1[i * 64 + j];
  __syncthreads();
  hs[rl][j] = a;
  __syncthreads();
  float u = r1b1[j];
  for (int i = 0; i < 64; i++) u += hs[rl][i] * r1W1[i * 64 + j];
  u = fmaxf(u, 0.f);
  ts[rl][j] = u;
  __syncthreads();
  float w = r1b2[j];
  for (int i = 0; i < 64; i++) w += ts[rl][i] * r1W2[i * 64 + j];
  w = fmaxf(w, 0.f) + hs[rl][j];
  __syncthreads();
  hs[rl][j] = w;
  __syncthreads();
  u = r2b1[j];
  for (int i = 0; i < 64; i++) u += hs[rl][i] * r2W1[i * 64 + j];
  u = fmaxf(u, 0.f);
  ts[rl][j] = u;
  __syncthreads();
  w = r2b2[j];
  for (int i = 0; i < 64; i++) w += ts[rl][i] * r2W2[i * 64 + j];
  w = fmaxf(w, 0.f) + hs[rl][j];
  __syncthreads();
  hs[rl][j] = w;
  __syncthreads();
  if (j < 2) {
    float o = sb2[j];
    for (int i = 0; i < 64; i++) o += hs[rl][i] * sW2[i * 2 + j];
    ts[rl][j] = o;
  }
  __syncthreads();
  if (j < 2) {
    float o0 = ts[rl][0], o1 = ts[rl][1];
    float mx = fmaxf(o0, o1);
    float l = mx + __logf(__expf(o0 - mx) + __expf(o1 - mx));
    if (j == 0) split0[c] = o0 - l;
    else        split1[c] = o1 - l;
  }
}

// ---------------------------------------------------------------------------
// K2: rule log_softmax + root scores + G tables (needs split0)
__global__ __launch_bounds__(256) void k_prelim(
    const float* __restrict__ rule_W, const float* __restrict__ rule_b,
    const float* __restrict__ root_W, const float* __restrict__ root_b,
    const float* __restrict__ split0,
    float* __restrict__ Gl, float* __restrict__ Gr, float* __restrict__ root36) {
  __shared__ float rs[36 * 72];
  __shared__ float lse4s;
  int tid = threadIdx.x;
  if (tid < 36) {
    float mx = -1e30f;
    for (int q = 0; q < 72; q++) mx = fmaxf(mx, rule_W[tid * 72 + q] + rule_b[q]);
    float ss = 0.f;
    for (int q = 0; q < 72; q++) ss += __expf(rule_W[tid * 72 + q] + rule_b[q] - mx);
    float l = mx + __logf(ss);
    for (int q = 0; q < 72; q++) rs[tid * 72 + q] = rule_W[tid * 72 + q] + rule_b[q] - l;
  }
  if (tid == 0) {
    float mx = -1e30f;
    for (int i = 0; i < 4; i++) mx = fmaxf(mx, root_W[i] + root_b[i]);
    float ss = 0.f;
    for (int i = 0; i < 4; i++) ss += __expf(root_W[i] + root_b[i] - mx);
    lse4s = mx + __logf(ss);
  }
  __syncthreads();
  if (tid < 36)
    root36[tid] = ((tid < 4) ? 0.f : NEGF) + root_W[tid] + root_b[tid] - lse4s;
  for (int i = tid; i < 1296; i += 256) {
    int arg = i / 36, res = i - arg * 36;
    float s0 = split0[res];
    Gl[i] = rs[res * 72 + arg] + s0;
    Gr[i] = rs[res * 72 + 36 + arg] + s0;
  }
}

// ---------------------------------------------------------------------------
// K3a: repack vocab_W into bf16 MFMA B-fragments.
__global__ __launch_bounds__(256) void k_cvt_w(
    const float* __restrict__ vocab_W, uint4* __restrict__ Wt) {
  int g = blockIdx.x * 256 + threadIdx.x;
  if (g >= NVT * 128) return;
  int l = g & 63;
  int f = (g >> 6) & 1;
  int vt = g >> 7;
  int v = vt * 16 + (l & 15);
  int kb = f * 32 + 8 * (l >> 4);
  uint32_t d[4];
#pragma unroll
  for (int p = 0; p < 4; p++) {
    float a = vocab_W[(size_t)(kb + 2 * p) * VV + v];
    float b = vocab_W[(size_t)(kb + 2 * p + 1) * VV + v];
    d[p] = f2bf_bits(a) | (f2bf_bits(b) << 16);
  }
  uint4 o; o.x = d[0]; o.y = d[1]; o.z = d[2]; o.w = d[3];
  Wt[g] = o;
}

// ---------------------------------------------------------------------------
// K3b: MFMA GEMM + fused exp-sum over V. Block = 4 waves, owns 64 C-rows.
__global__ __launch_bounds__(256) void k_lse_mfma(
    const float* __restrict__ nt_emb, const uint4* __restrict__ Wt,
    const float* __restrict__ vocab_b, float* __restrict__ lseacc) {
  int tid = threadIdx.x;
  int w = tid >> 6, l = tid & 63;
  int c0 = blockIdx.y * 64;
  int lrow = l & 15, lgrp = l >> 4;

  bf16x8 A[4][2];
#pragma unroll
  for (int ct = 0; ct < 4; ct++) {
    int row = c0 + ct * 16 + lrow;
#pragma unroll
    for (int kf = 0; kf < 2; kf++) {
      bf16x8 fr;
      if (row < CT) {
        const float4* src = (const float4*)(nt_emb + (size_t)row * 64 + kf * 32 + lgrp * 8);
        float4 s0 = src[0], s1 = src[1];
        fr[0] = (short)f2bf_bits(s0.x); fr[1] = (short)f2bf_bits(s0.y);
        fr[2] = (short)f2bf_bits(s0.z); fr[3] = (short)f2bf_bits(s0.w);
        fr[4] = (short)f2bf_bits(s1.x); fr[5] = (short)f2bf_bits(s1.y);
        fr[6] = (short)f2bf_bits(s1.z); fr[7] = (short)f2bf_bits(s1.w);
      } else {
#pragma unroll
        for (int e = 0; e < 8; e++) fr[e] = 0;
      }
      A[ct][kf] = fr;
    }
  }

  float sums[4][4];
#pragma unroll
  for (int ct = 0; ct < 4; ct++)
#pragma unroll
    for (int i = 0; i < 4; i++) sums[ct][i] = 0.f;

  int tend = (blockIdx.x + 1) * (NVT / 8);
  for (int t = blockIdx.x * (NVT / 8) + w; t < tend; t += 4) {
    union { uint4 u; bf16x8 h; } b0, b1;
    b0.u = Wt[(size_t)(t * 2) * 64 + l];
    b1.u = Wt[(size_t)(t * 2 + 1) * 64 + l];
    float vb = vocab_b[t * 16 + lrow];
#pragma unroll
    for (int ct = 0; ct < 4; ct++) {
      f32x4 acc = {0.f, 0.f, 0.f, 0.f};
      acc = __builtin_amdgcn_mfma_f32_16x16x32_bf16(A[ct][0], b0.h, acc, 0, 0, 0);
      acc = __builtin_amdgcn_mfma_f32_16x16x32_bf16(A[ct][1], b1.h, acc, 0, 0, 0);
#pragma unroll
      for (int i = 0; i < 4; i++) sums[ct][i] += __expf(acc[i] + vb);
    }
  }

#pragma unroll
  for (int ct = 0; ct < 4; ct++)
#pragma unroll
    for (int i = 0; i < 4; i++) {
      float v = sums[ct][i];
      v += __shfl_xor(v, 1);
      v += __shfl_xor(v, 2);
      v += __shfl_xor(v, 4);
      v += __shfl_xor(v, 8);
      sums[ct][i] = v;
    }
  if (lrow == 0) {
#pragma unroll
    for (int ct = 0; ct < 4; ct++)
#pragma unroll
      for (int i = 0; i < 4; i++) {
        int row = c0 + ct * 16 + lgrp * 4 + i;
        if (row < CT) atomicAdd(&lseacc[row], sums[ct][i]);
      }
  }
}

// ---------------------------------------------------------------------------
// K5: beta1[n,b,c] = logit(c, x[b,n]) - log(lseacc[c]) + split1[c]
__global__ __launch_bounds__(256) void k_beta1(
    const float* __restrict__ nt_emb, const float* __restrict__ vocab_W,
    const float* __restrict__ vocab_b, const int* __restrict__ x,
    const float* __restrict__ lseacc, const float* __restrict__ split1,
    float* __restrict__ beta1) {
  __shared__ float nt[16][64];
  __shared__ float lseS[16], sp1S[16];
  int tid = threadIdx.x;
  int c0 = blockIdx.x * 16;
  int nr = min(16, CT - c0);
  for (int i = tid; i < 1024; i += 256) {
    int r = i >> 6, d = i & 63;
    nt[r][d] = (r < nr) ? nt_emb[(size_t)(c0 + r) * 64 + d] : 0.f;
  }
  if (tid < 16) {
    lseS[tid] = (tid < nr) ? __logf(lseacc[c0 + tid]) : 0.f;
    sp1S[tid] = (tid < nr) ? split1[c0 + tid] : 0.f;
  }
  __syncthreads();
  for (int j = tid; j < BB * NN; j += 256) {
    int tok = x[j];
    float acc[16];
#pragma unroll
    for (int r = 0; r < 16; r++) acc[r] = 0.f;
#pragma unroll 4
    for (int d = 0; d < 64; d++) {
      float vw = vocab_W[(size_t)d * VV + tok];
#pragma unroll
      for (int r = 0; r < 16; r++) acc[r] = fmaf(nt[r][d], vw, acc[r]);
    }
    float vb = vocab_b[tok];
    int b = j >> 5, np = j & 31;
    size_t basei = ((size_t)(np * 32 + b)) * CT + c0;
    for (int r = 0; r < nr; r++)
      beta1[basei + r] = acc[r] + vb - lseS[r] + sp1S[r];
  }
}

// ---------------------------------------------------------------------------
// K6: EXP-space edge tables, bf16-pair packed, layout [sb][res][p] p-stride 20.
// elp[sb*720 + res*20 + p] packs exp(beta1[s,b,lf[2p,res]]+Gr[2p,res]) (lo)
//                             and exp(beta1[s,b,lf[2p+1,res]]+Gr[2p+1,res]) (hi)
__global__ __launch_bounds__(256) void k_edge(
    const float* __restrict__ beta1, const int* __restrict__ lf_t,
    const int* __restrict__ rf_t, const float* __restrict__ Gl,
    const float* __restrict__ Gr,
    uint32_t* __restrict__ elp, uint32_t* __restrict__ erp) {
  int sb = blockIdx.x;
  const float* brow = beta1 + (size_t)sb * CT;
  size_t ob = (size_t)sb * 720;
  for (int j = threadIdx.x; j < 648; j += 256) {
    int res = j / 18, p = j - res * 18;
    int i0 = (2 * p) * 36 + res, i1 = i0 + 36;
    float e0 = __expf(brow[lf_t[i0]] + Gr[i0]);
    float e1 = __expf(brow[lf_t[i1]] + Gr[i1]);
    elp[ob + res * 20 + p] = f2bf_bits(e0) | (f2bf_bits(e1) << 16);
    e0 = __expf(brow[rf_t[i0]] + Gl[i0]);
    e1 = __expf(brow[rf_t[i1]] + Gl[i1]);
    erp[ob + res * 20 + p] = f2bf_bits(e0) | (f2bf_bits(e1) << 16);
  }
}

// ---------------------------------------------------------------------------
// K7: CKY inside pass, EXP-space, vectorized. One block per batch element.
__global__ __launch_bounds__(1024, 4) void k_cky(
    const float* __restrict__ beta1, const uint4* __restrict__ elp,
    const uint4* __restrict__ erp, const float* __restrict__ Gl,
    const float* __restrict__ Gr, const float* __restrict__ root36,
    float* __restrict__ out) {
  __shared__ __align__(16) float D[19008];
  __shared__ float Mt[528];
  __shared__ __align__(16) float PA[1116], PB[1116];
  __shared__ float cand[33];
  __shared__ __align__(16) float Ec1lT[512], Ec1rT[512]; // [s][res][a]
  __shared__ __align__(16) float eGlT[16], eGrT[16];     // [res][a]

  int b = blockIdx.x, tid = threadIdx.x;
  int wid = tid >> 6, lane = tid & 63;

  for (int i = tid; i < 32 * 36; i += 1024) {
    int s = i / 36, j = i - s * 36;
    D[i] = __expf(beta1[(size_t)(s * 32 + b) * CT + j]);
  }
  if (tid < 32) Mt[tid] = 0.f;
  if (tid < 16) {
    int res = tid >> 2, a = tid & 3;
    eGlT[tid] = __expf(Gl[a * 36 + res]);
    eGrT[tid] = __expf(Gr[a * 36 + res]);
  }
  __syncthreads();
  for (int i = tid; i < 512; i += 1024) {
    int s = i >> 4, rr = (i >> 2) & 3, a = i & 3;
    float d1 = D[s * 36 + a];
    Ec1lT[i] = d1 * eGlT[rr * 4 + a];
    Ec1rT[i] = d1 * eGrT[rr * 4 + a];
  }
  __syncthreads();

  for (int L = 2; L <= 32; L++) {
    int S = 33 - L;
    int offL   = 36 * (((L - 1) * (66 - L)) >> 1);
    int offP   = 36 * (((L - 2) * (67 - L)) >> 1);
    int offML  = ((L - 1) * (66 - L)) >> 1;
    int offMP  = ((L - 2) * (67 - L)) >> 1;

    // phase 1a: cand[s'] = M[L-1][s'] + log(max_a D[L-1][s'][a])
    for (int sp = wid; sp <= S; sp += 16) {
      float v = (lane < 36) ? D[offP + sp * 36 + lane] : 0.f;
#pragma unroll
      for (int w = 32; w > 0; w >>= 1) v = fmaxf(v, __shfl_xor(v, w));
      v = fmaxf(v, 1e-37f);
      if (lane == 0) cand[sp] = Mt[offMP + sp] + __logf(v);
    }
    __syncthreads();
    // phase 1b: Mnew[s], P arrays
    for (int s = wid; s < S; s += 16) {
      float Mn = fmaxf(cand[s], cand[s + 1]);
      float fA = __expf(Mt[offMP + s] - Mn);
      float fB = __expf(Mt[offMP + s + 1] - Mn);
      if (lane < 36) {
        PA[s * 36 + lane] = D[offP + s * 36 + lane] * fA;
        PB[s * 36 + lane] = D[offP + (s + 1) * 36 + lane] * fB;
      }
      if (lane == 0) Mt[offML + s] = Mn;
    }
    __syncthreads();

    // phase 2: mains (o < tot) + corner mids (o >= tot, one thread per (s,res<4))
    int tot = S * 36;
    int W = tot + ((L >= 4) ? 4 * S : 0);
    int mido = -1;
    float midv = 0.f;
    for (int o = tid; o < W; o += 1024) {
      if (o < tot) {
        int s = o / 36, res = o - s * 36;
        const uint4* el4 = elp + (size_t)(s * 32 + b) * 45 + res * 5;
        const uint4* er4 = erp + (size_t)((s + L - 1) * 32 + b) * 45 + res * 5;
        const float4* pB4 = (const float4*)(PB + s * 36);
        const float4* pA4 = (const float4*)(PA + s * 36);
        float a0 = 0.f, a1 = 0.f, a2 = 0.f, a3 = 0.f;
#pragma unroll
        for (int q = 0; q < 4; q++) {
          uint4 u = el4[q];
          float4 f0 = pB4[2 * q], f1 = pB4[2 * q + 1];
          a0 = fmaf(f0.x, bflo(u.x), a0); a1 = fmaf(f0.y, bfhi(u.x), a1);
          a2 = fmaf(f0.z, bflo(u.y), a2); a3 = fmaf(f0.w, bfhi(u.y), a3);
          a0 = fmaf(f1.x, bflo(u.z), a0); a1 = fmaf(f1.y, bfhi(u.z), a1);
          a2 = fmaf(f1.z, bflo(u.w), a2); a3 = fmaf(f1.w, bfhi(u.w), a3);
          uint4 w = er4[q];
          float4 g0 = pA4[2 * q], g1 = pA4[2 * q + 1];
          a0 = fmaf(g0.x, bflo(w.x), a0); a1 = fmaf(g0.y, bfhi(w.x), a1);
          a2 = fmaf(g0.z, bflo(w.y), a2); a3 = fmaf(g0.w, bfhi(w.y), a3);
          a0 = fmaf(g1.x, bflo(w.z), a0); a1 = fmaf(g1.y, bfhi(w.z), a1);
          a2 = fmaf(g1.z, bflo(w.w), a2); a3 = fmaf(g1.w, bfhi(w.w), a3);
        }
        {   // tail p = 16,17
          uint4 t = el4[4]; float4 f8 = pB4[8];
          a0 = fmaf(f8.x, bflo(t.x), a0); a1 = fmaf(f8.y, bfhi(t.x), a1);
          a2 = fmaf(f8.z, bflo(t.y), a2); a3 = fmaf(f8.w, bfhi(t.y), a3);
          uint4 tw = er4[4]; float4 g8 = pA4[8];
          a0 = fmaf(g8.x, bflo(tw.x), a0); a1 = fmaf(g8.y, bfhi(tw.x), a1);
          a2 = fmaf(g8.z, bflo(tw.y), a2); a3 = fmaf(g8.w, bfhi(tw.y), a3);
        }
        if (res < 4 && L >= 3) {   // adjacency corners (k=1 branchA, k=L-1 branchB)
          const float4* ecl = (const float4*)(Ec1lT + s * 16 + res * 4);
          const float4* ecr = (const float4*)(Ec1rT + (s + L - 1) * 16 + res * 4);
          float4 e0 = ecl[0], pb = pB4[5 + res];
          float4 e1 = ecr[0], pa = pA4[1 + res];
          a0 = fmaf(e0.x, pb.x, a0); a1 = fmaf(e0.y, pb.y, a1);
          a2 = fmaf(e0.z, pb.z, a2); a3 = fmaf(e0.w, pb.w, a3);
          a0 = fmaf(e1.x, pa.x, a0); a1 = fmaf(e1.y, pa.y, a1);
          a2 = fmaf(e1.z, pa.z, a2); a3 = fmaf(e1.w, pa.w, a3);
        }
        D[offL + o] = (a0 + a1) + (a2 + a3);
      } else {
        // mid item: (s, res<4), serial over k=2..L-2
        int o2 = o - tot;
        int s = o2 >> 2, res = o2 & 3;
        float Mn = Mt[offML + s];
        float4 egl = ((const float4*)eGlT)[res];
        float4 egr = ((const float4*)eGrT)[res];
        float mv = 0.f;
        for (int k = 2; k <= L - 2; k++) {
          int tk = ((k - 1) * (66 - k)) >> 1;
          int tl = ((L - k - 1) * (66 - (L - k))) >> 1;
          const float4* Dk4 = (const float4*)(D + 36 * tk + s * 36);
          const float4* Dl4 = (const float4*)(D + 36 * tl + (s + k) * 36);
          float4 dk0 = Dk4[0], dkh = Dk4[1 + res];
          float4 dl0 = Dl4[0], dlh = Dl4[5 + res];
          float f = __expf(Mt[tk + s] + Mt[tl + s + k] - Mn);
          float sub = dk0.x * dlh.x * egl.x + dk0.y * dlh.y * egl.y
                    + dk0.z * dlh.z * egl.z + dk0.w * dlh.w * egl.w
                    + dl0.x * dkh.x * egr.x + dl0.y * dkh.y * egr.y
                    + dl0.z * dkh.z * egr.z + dl0.w * dkh.w * egr.w;
          mv = fmaf(f, sub, mv);
        }
        midv = mv;
        mido = offL + s * 36 + res;
      }
    }
    __syncthreads();
    if (mido >= 0) D[mido] += midv;
    __syncthreads();
  }

  if (wid == 0) {
    int off32 = 36 * ((31 * 34) >> 1);
    float v = (lane < 36) ? D[off32 + lane] * __expf(root36[lane]) : 0.f;
#pragma unroll
    for (int w = 32; w > 0; w >>= 1) v += __shfl_xor(v, w);
    if (lane == 0) out[b] = -(Mt[527] + __logf(v));
  }
}

// ---------------------------------------------------------------------------
extern "C" void kernel_launch(void* const* d_in, const int* in_sizes, int n_in,
                              void* d_out, int out_size, void* d_ws, size_t ws_size,
                              hipStream_t stream) {
  const int*   x       = (const int*)d_in[0];
  const int*   lf_t    = (const int*)d_in[1];
  const int*   rf_t    = (const int*)d_in[2];
  const float* root_W  = (const float*)d_in[3];
  const float* root_b  = (const float*)d_in[4];
  const float* rule_W  = (const float*)d_in[5];
  const float* rule_b  = (const float*)d_in[6];
  const float* nt_emb  = (const float*)d_in[7];
  const float* sW1     = (const float*)d_in[8];
  const float* sb1     = (const float*)d_in[9];
  const float* r1W1    = (const float*)d_in[10];
  const float* r1b1    = (const float*)d_in[11];
  const float* r1W2    = (const float*)d_in[12];
  const float* r1b2    = (const float*)d_in[13];
  const float* r2W1    = (const float*)d_in[14];
  const float* r2b1    = (const float*)d_in[15];
  const float* r2W2    = (const float*)d_in[16];
  const float* r2b2    = (const float*)d_in[17];
  const float* sW2     = (const float*)d_in[18];
  const float* sb2     = (const float*)d_in[19];
  const float* vocab_W = (const float*)d_in[20];
  const float* vocab_b = (const float*)d_in[21];
  float* outp = (float*)d_out;

  float* ws = (float*)d_ws;
  float* split0 = ws;                         // 2596
  float* split1 = ws + 2596;                  // 2596
  float* Gl     = ws + 5192;                  // 1296
  float* Gr     = ws + 6488;                  // 1296
  float* root36 = ws + 7784;                  // 64 (pad)
  float* lseacc = ws + 7848;                  // 2596 -> pad to 13040
  float* beta1  = ws + 13040;                 // 2658304 -> end 2671344
  uint32_t* elp = (uint32_t*)(ws + 2671344);  // 1024*720 = 737280 u32
  uint32_t* erp = (uint32_t*)(ws + 3408624);  // 737280 u32 -> end 4145904
  uint4*    Wt  = (uint4*)(ws + 4145904);     // 256000 uint4 -> end 5169904 floats

  k_mlp<<<649, 256, 0, stream>>>(nt_emb, sW1, sb1, r1W1, r1b1, r1W2, r1b2,
                                 r2W1, r2b1, r2W2, r2b2, sW2, sb2, split0, split1);
  k_prelim<<<1, 256, 0, stream>>>(rule_W, rule_b, root_W, root_b, split0, Gl, Gr, root36);
  k_cvt_w<<<1000, 256, 0, stream>>>(vocab_W, Wt);
  hipMemsetAsync(lseacc, 0, CT * sizeof(float), stream);
  k_lse_mfma<<<dim3(8, 41), 256, 0, stream>>>(nt_emb, Wt, vocab_b, lseacc);
  k_beta1<<<163, 256, 0, stream>>>(nt_emb, vocab_W, vocab_b, x, lseacc, split1, beta1);
  k_edge<<<1024, 256, 0, stream>>>(beta1, lf_t, rf_t, Gl, Gr, elp, erp);
  k_cky<<<32, 1024, 0, stream>>>(beta1, (const uint4*)elp, (const uint4*)erp,
                                 Gl, Gr, root36, outp);
}

// Round 5
// 264.115 us; speedup vs baseline: 2.9349x; 1.0926x over previous
//
#include <hip/hip_runtime.h>
#include <hip/hip_bf16.h>
#include <math.h>

#define CT 2596      // total functor count C
#define NF36 36
#define BB 32        // batch
#define NN 32        // seq len
#define VV 32000
#define DD 64
#define NEGF -1e9f
#define NVT 2000     // V tiles of 16

typedef __attribute__((ext_vector_type(8))) short bf16x8;
typedef __attribute__((ext_vector_type(4))) float f32x4;

__device__ __forceinline__ void lse_acc(float& m, float& s, float v) {
  float nm = fmaxf(m, v);
  s = s * __expf(m - nm) + __expf(v - nm);
  m = nm;
}

// bf16 helpers
__device__ __forceinline__ uint32_t f2bf_bits(float x) {
  union { float f; uint32_t u; } v; v.f = x;
  return (v.u + 0x7FFFu + ((v.u >> 16) & 1u)) >> 16;   // RNE
}

// ---------------------------------------------------------------------------
// K1: MLP over all C rows -> split0[c], split1[c]
__global__ __launch_bounds__(256) void k_mlp(
    const float* __restrict__ nt_emb,
    const float* __restrict__ sW1, const float* __restrict__ sb1,
    const float* __restrict__ r1W1, const float* __restrict__ r1b1,
    const float* __restrict__ r1W2, const float* __restrict__ r1b2,
    const float* __restrict__ r2W1, const float* __restrict__ r2b1,
    const float* __restrict__ r2W2, const float* __restrict__ r2b2,
    const float* __restrict__ sW2, const float* __restrict__ sb2,
    float* __restrict__ split0, float* __restrict__ split1) {
  int tid = threadIdx.x;
  int rl = tid >> 6, j = tid & 63;
  int c = blockIdx.x * 4 + rl;
  __shared__ float hs[4][64], ts[4][64];

  ts[rl][j] = nt_emb[(size_t)c * 64 + j];
  __syncthreads();
  float a = sb1[j];
  for (int i = 0; i < 64; i++) a += ts[rl][i] * sW1[i * 64 + j];
  __syncthreads();
  hs[rl][j] = a;
  __syncthreads();
  float u = r1b1[j];
  for (int i = 0; i < 64; i++) u += hs[rl][i] * r1W1[i * 64 + j];
  u = fmaxf(u, 0.f);
  ts[rl][j] = u;
  __syncthreads();
  float w = r1b2[j];
  for (int i = 0; i < 64; i++) w += ts[rl][i] * r1W2[i * 64 + j];
  w = fmaxf(w, 0.f) + hs[rl][j];
  __syncthreads();
  hs[rl][j] = w;
  __syncthreads();
  u = r2b1[j];
  for (int i = 0; i < 64; i++) u += hs[rl][i] * r2W1[i * 64 + j];
  u = fmaxf(u, 0.f);
  ts[rl][j] = u;
  __syncthreads();
  w = r2b2[j];
  for (int i = 0; i < 64; i++) w += ts[rl][i] * r2W2[i * 64 + j];
  w = fmaxf(w, 0.f) + hs[rl][j];
  __syncthreads();
  hs[rl][j] = w;
  __syncthreads();
  if (j < 2) {
    float o = sb2[j];
    for (int i = 0; i < 64; i++) o += hs[rl][i] * sW2[i * 2 + j];
    ts[rl][j] = o;
  }
  __syncthreads();
  if (j < 2) {
    float o0 = ts[rl][0], o1 = ts[rl][1];
    float mx = fmaxf(o0, o1);
    float l = mx + __logf(__expf(o0 - mx) + __expf(o1 - mx));
    if (j == 0) split0[c] = o0 - l;
    else        split1[c] = o1 - l;
  }
}

// ---------------------------------------------------------------------------
// K2: rule log_softmax + root scores + G tables (needs split0)
__global__ __launch_bounds__(256) void k_prelim(
    const float* __restrict__ rule_W, const float* __restrict__ rule_b,
    const float* __restrict__ root_W, const float* __restrict__ root_b,
    const float* __restrict__ split0,
    float* __restrict__ Gl, float* __restrict__ Gr, float* __restrict__ root36) {
  __shared__ float rs[36 * 72];
  __shared__ float lse4s;
  int tid = threadIdx.x;
  if (tid < 36) {
    float mx = -1e30f;
    for (int q = 0; q < 72; q++) mx = fmaxf(mx, rule_W[tid * 72 + q] + rule_b[q]);
    float ss = 0.f;
    for (int q = 0; q < 72; q++) ss += __expf(rule_W[tid * 72 + q] + rule_b[q] - mx);
    float l = mx + __logf(ss);
    for (int q = 0; q < 72; q++) rs[tid * 72 + q] = rule_W[tid * 72 + q] + rule_b[q] - l;
  }
  if (tid == 0) {
    float mx = -1e30f;
    for (int i = 0; i < 4; i++) mx = fmaxf(mx, root_W[i] + root_b[i]);
    float ss = 0.f;
    for (int i = 0; i < 4; i++) ss += __expf(root_W[i] + root_b[i] - mx);
    lse4s = mx + __logf(ss);
  }
  __syncthreads();
  if (tid < 36)
    root36[tid] = ((tid < 4) ? 0.f : NEGF) + root_W[tid] + root_b[tid] - lse4s;
  for (int i = tid; i < 1296; i += 256) {
    int arg = i / 36, res = i - arg * 36;
    float s0 = split0[res];
    Gl[i] = rs[res * 72 + arg] + s0;
    Gr[i] = rs[res * 72 + 36 + arg] + s0;
  }
}

// ---------------------------------------------------------------------------
// K3a: repack vocab_W into bf16 MFMA B-fragments.
__global__ __launch_bounds__(256) void k_cvt_w(
    const float* __restrict__ vocab_W, uint4* __restrict__ Wt) {
  int g = blockIdx.x * 256 + threadIdx.x;
  if (g >= NVT * 128) return;
  int l = g & 63;
  int f = (g >> 6) & 1;
  int vt = g >> 7;
  int v = vt * 16 + (l & 15);
  int kb = f * 32 + 8 * (l >> 4);
  uint32_t d[4];
#pragma unroll
  for (int p = 0; p < 4; p++) {
    float a = vocab_W[(size_t)(kb + 2 * p) * VV + v];
    float b = vocab_W[(size_t)(kb + 2 * p + 1) * VV + v];
    d[p] = f2bf_bits(a) | (f2bf_bits(b) << 16);
  }
  uint4 o; o.x = d[0]; o.y = d[1]; o.z = d[2]; o.w = d[3];
  Wt[g] = o;
}

// ---------------------------------------------------------------------------
// K3b: MFMA GEMM + fused exp-sum over V. Block = 4 waves, owns 64 C-rows.
__global__ __launch_bounds__(256) void k_lse_mfma(
    const float* __restrict__ nt_emb, const uint4* __restrict__ Wt,
    const float* __restrict__ vocab_b, float* __restrict__ lseacc) {
  int tid = threadIdx.x;
  int w = tid >> 6, l = tid & 63;
  int c0 = blockIdx.y * 64;
  int lrow = l & 15, lgrp = l >> 4;

  bf16x8 A[4][2];
#pragma unroll
  for (int ct = 0; ct < 4; ct++) {
    int row = c0 + ct * 16 + lrow;
#pragma unroll
    for (int kf = 0; kf < 2; kf++) {
      bf16x8 fr;
      if (row < CT) {
        const float4* src = (const float4*)(nt_emb + (size_t)row * 64 + kf * 32 + lgrp * 8);
        float4 s0 = src[0], s1 = src[1];
        fr[0] = (short)f2bf_bits(s0.x); fr[1] = (short)f2bf_bits(s0.y);
        fr[2] = (short)f2bf_bits(s0.z); fr[3] = (short)f2bf_bits(s0.w);
        fr[4] = (short)f2bf_bits(s1.x); fr[5] = (short)f2bf_bits(s1.y);
        fr[6] = (short)f2bf_bits(s1.z); fr[7] = (short)f2bf_bits(s1.w);
      } else {
#pragma unroll
        for (int e = 0; e < 8; e++) fr[e] = 0;
      }
      A[ct][kf] = fr;
    }
  }

  float sums[4][4];
#pragma unroll
  for (int ct = 0; ct < 4; ct++)
#pragma unroll
    for (int i = 0; i < 4; i++) sums[ct][i] = 0.f;

  int tend = (blockIdx.x + 1) * (NVT / 8);
  for (int t = blockIdx.x * (NVT / 8) + w; t < tend; t += 4) {
    union { uint4 u; bf16x8 h; } b0, b1;
    b0.u = Wt[(size_t)(t * 2) * 64 + l];
    b1.u = Wt[(size_t)(t * 2 + 1) * 64 + l];
    float vb = vocab_b[t * 16 + lrow];
#pragma unroll
    for (int ct = 0; ct < 4; ct++) {
      f32x4 acc = {0.f, 0.f, 0.f, 0.f};
      acc = __builtin_amdgcn_mfma_f32_16x16x32_bf16(A[ct][0], b0.h, acc, 0, 0, 0);
      acc = __builtin_amdgcn_mfma_f32_16x16x32_bf16(A[ct][1], b1.h, acc, 0, 0, 0);
#pragma unroll
      for (int i = 0; i < 4; i++) sums[ct][i] += __expf(acc[i] + vb);
    }
  }

#pragma unroll
  for (int ct = 0; ct < 4; ct++)
#pragma unroll
    for (int i = 0; i < 4; i++) {
      float v = sums[ct][i];
      v += __shfl_xor(v, 1);
      v += __shfl_xor(v, 2);
      v += __shfl_xor(v, 4);
      v += __shfl_xor(v, 8);
      sums[ct][i] = v;
    }
  if (lrow == 0) {
#pragma unroll
    for (int ct = 0; ct < 4; ct++)
#pragma unroll
      for (int i = 0; i < 4; i++) {
        int row = c0 + ct * 16 + lgrp * 4 + i;
        if (row < CT) atomicAdd(&lseacc[row], sums[ct][i]);
      }
  }
}

// ---------------------------------------------------------------------------
// K5: beta1[n,b,c] = logit(c, x[b,n]) - log(lseacc[c]) + split1[c]
__global__ __launch_bounds__(256) void k_beta1(
    const float* __restrict__ nt_emb, const float* __restrict__ vocab_W,
    const float* __restrict__ vocab_b, const int* __restrict__ x,
    const float* __restrict__ lseacc, const float* __restrict__ split1,
    float* __restrict__ beta1) {
  __shared__ float nt[16][64];
  __shared__ float lseS[16], sp1S[16];
  int tid = threadIdx.x;
  int c0 = blockIdx.x * 16;
  int nr = min(16, CT - c0);
  for (int i = tid; i < 1024; i += 256) {
    int r = i >> 6, d = i & 63;
    nt[r][d] = (r < nr) ? nt_emb[(size_t)(c0 + r) * 64 + d] : 0.f;
  }
  if (tid < 16) {
    lseS[tid] = (tid < nr) ? __logf(lseacc[c0 + tid]) : 0.f;
    sp1S[tid] = (tid < nr) ? split1[c0 + tid] : 0.f;
  }
  __syncthreads();
  for (int j = tid; j < BB * NN; j += 256) {
    int tok = x[j];
    float acc[16];
#pragma unroll
    for (int r = 0; r < 16; r++) acc[r] = 0.f;
#pragma unroll 4
    for (int d = 0; d < 64; d++) {
      float vw = vocab_W[(size_t)d * VV + tok];
#pragma unroll
      for (int r = 0; r < 16; r++) acc[r] = fmaf(nt[r][d], vw, acc[r]);
    }
    float vb = vocab_b[tok];
    int b = j >> 5, np = j & 31;
    size_t basei = ((size_t)(np * 32 + b)) * CT + c0;
    for (int r = 0; r < nr; r++)
      beta1[basei + r] = acc[r] + vb - lseS[r] + sp1S[r];
  }
}

// ---------------------------------------------------------------------------
// K6: EXP-space edge tables, fp32, layout [sb][res][arg] (contiguous per res).
// elF[sb*1296 + res*36 + arg] = exp(beta1[s,b, lf[arg,res]] + Gr[arg,res])
// erF[sb*1296 + res*36 + arg] = exp(beta1[s,b, rf[arg,res]] + Gl[arg,res])
__global__ __launch_bounds__(256) void k_edge(
    const float* __restrict__ beta1, const int* __restrict__ lf_t,
    const int* __restrict__ rf_t, const float* __restrict__ Gl,
    const float* __restrict__ Gr,
    float* __restrict__ elF, float* __restrict__ erF) {
  int sb = blockIdx.x;
  const float* brow = beta1 + (size_t)sb * CT;
  size_t ob = (size_t)sb * 1296;
  for (int j = threadIdx.x; j < 1296; j += 256) {
    int res = j / 36, arg = j - res * 36;
    int i = arg * 36 + res;
    elF[ob + j] = __expf(brow[lf_t[i]] + Gr[i]);
    erF[ob + j] = __expf(brow[rf_t[i]] + Gl[i]);
  }
}

// ---------------------------------------------------------------------------
// K7: CKY inside pass, EXP-space. One block per batch element.
// 3 phases/level: A (scale prev row into PA/PB, online max via candb),
// 2 (mains = 36-dot via fp32 tables; mids = parallel-over-k corner terms),
// 3 (merge MIDacc into D).
__global__ __launch_bounds__(1024, 4) void k_cky(
    const float* __restrict__ beta1, const float* __restrict__ elF,
    const float* __restrict__ erF, const float* __restrict__ Gl,
    const float* __restrict__ Gr, const float* __restrict__ root36,
    float* __restrict__ out) {
  __shared__ __align__(16) float D[19008];
  __shared__ float Mt[528];
  __shared__ __align__(16) float PA[1152], PB[1152];
  __shared__ __align__(16) float Ec1lT[512], Ec1rT[512]; // [s][res][a]
  __shared__ __align__(16) float eGlT[16], eGrT[16];     // [res][a]
  __shared__ unsigned int candb[2][33];                  // row max bits, by parity
  __shared__ float MIDacc[128];

  int b = blockIdx.x, tid = threadIdx.x;

  if (tid < 66) candb[tid / 33][tid % 33] = 0u;
  if (tid < 32) Mt[tid] = 0.f;
  if (tid < 16) {
    int res = tid >> 2, a = tid & 3;
    eGlT[tid] = __expf(Gl[a * 36 + res]);
    eGrT[tid] = __expf(Gr[a * 36 + res]);
  }
  __syncthreads();
  // level 1 init + candb[parity 1]
  for (int i = tid; i < 32 * 36; i += 1024) {
    int s = i / 36;
    float v = __expf(beta1[(size_t)(s * 32 + b) * CT + (i - s * 36)]);
    D[i] = v;
    atomicMax(&candb[1][s], __float_as_uint(v));
  }
  __syncthreads();
  for (int i = tid; i < 512; i += 1024) {
    int s = i >> 4, rr = (i >> 2) & 3, a = i & 3;
    float d1 = D[s * 36 + a];
    Ec1lT[i] = d1 * eGlT[rr * 4 + a];
    Ec1rT[i] = d1 * eGrT[rr * 4 + a];
  }
  __syncthreads();

  for (int L = 2; L <= 32; L++) {
    int S = 33 - L;
    int offL  = 36 * (((L - 1) * (66 - L)) >> 1);
    int offP  = 36 * (((L - 2) * (67 - L)) >> 1);
    int offML = ((L - 1) * (66 - L)) >> 1;
    int offMP = ((L - 2) * (67 - L)) >> 1;
    int par = L & 1, parP = par ^ 1;

    // ---- phase A: scaling + PA/PB; zero candb[par] and MIDacc
    if (tid < 33) candb[par][tid] = 0u;
    if (tid >= 64 && tid < 192) MIDacc[tid - 64] = 0.f;
    int totA = S * 36;
    for (int o = tid; o < totA; o += 1024) {
      int s = o / 36, j = o - s * 36;
      float MtA = Mt[offMP + s], MtB = Mt[offMP + s + 1];
      float cA = MtA + __logf(fmaxf(__uint_as_float(candb[parP][s]), 1e-37f));
      float cB = MtB + __logf(fmaxf(__uint_as_float(candb[parP][s + 1]), 1e-37f));
      float Mn = fmaxf(cA, cB);
      PA[s * 36 + j] = D[offP + s * 36 + j] * __expf(MtA - Mn);
      PB[s * 36 + j] = D[offP + (s + 1) * 36 + j] * __expf(MtB - Mn);
      if (j == 0) Mt[offML + s] = Mn;
    }
    __syncthreads();

    // ---- phase 2: mains + parallel mids
    int tot = S * 36;
    int nmid = (L >= 4) ? 4 * S * (L - 3) : 0;
    int W = tot + nmid;
    for (int o = tid; o < W; o += 1024) {
      if (o < tot) {
        int s = o / 36, res = o - s * 36;
        const float4* el4 = (const float4*)(elF + (size_t)(s * 32 + b) * 1296 + res * 36);
        const float4* er4 = (const float4*)(erF + (size_t)((s + L - 1) * 32 + b) * 1296 + res * 36);
        const float4* pB4 = (const float4*)(PB + s * 36);
        const float4* pA4 = (const float4*)(PA + s * 36);
        float a0 = 0.f, a1 = 0.f, a2 = 0.f, a3 = 0.f;
#pragma unroll
        for (int q = 0; q < 9; q++) {
          float4 e = el4[q], p = pB4[q];
          a0 = fmaf(e.x, p.x, a0); a1 = fmaf(e.y, p.y, a1);
          a2 = fmaf(e.z, p.z, a2); a3 = fmaf(e.w, p.w, a3);
          float4 r = er4[q], pa = pA4[q];
          a0 = fmaf(r.x, pa.x, a0); a1 = fmaf(r.y, pa.y, a1);
          a2 = fmaf(r.z, pa.z, a2); a3 = fmaf(r.w, pa.w, a3);
        }
        if (res < 4 && L >= 3) {   // adjacency corners (k=1 branchA, k=L-1 branchB)
          const float4* ecl = (const float4*)(Ec1lT + s * 16 + res * 4);
          const float4* ecr = (const float4*)(Ec1rT + (s + L - 1) * 16 + res * 4);
          float4 e0 = ecl[0], pb = pB4[5 + res];
          float4 e1 = ecr[0], pa = pA4[1 + res];
          a0 = fmaf(e0.x, pb.x, a0); a1 = fmaf(e0.y, pb.y, a1);
          a2 = fmaf(e0.z, pb.z, a2); a3 = fmaf(e0.w, pb.w, a3);
          a0 = fmaf(e1.x, pa.x, a0); a1 = fmaf(e1.y, pa.y, a1);
          a2 = fmaf(e1.z, pa.z, a2); a3 = fmaf(e1.w, pa.w, a3);
        }
        float val = (a0 + a1) + (a2 + a3);
        D[offL + o] = val;
        atomicMax(&candb[par][s], __float_as_uint(val));
      } else {
        // mid item (s, res<4, k): one k per thread, no serial chain
        int o2 = o - tot;
        int kidx = o2 / (4 * S);
        int rem = o2 - kidx * 4 * S;
        int s = rem >> 2, res = rem & 3;
        int k = kidx + 2;
        int lk = L - k;
        int tk = ((k - 1) * (66 - k)) >> 1;
        int tl = ((lk - 1) * (66 - lk)) >> 1;
        const float4* Dk4 = (const float4*)(D + 36 * tk + s * 36);
        const float4* Dl4 = (const float4*)(D + 36 * tl + (s + k) * 36);
        float4 dk0 = Dk4[0], dkh = Dk4[1 + res];
        float4 dl0 = Dl4[0], dlh = Dl4[5 + res];
        float4 egl = ((const float4*)eGlT)[res];
        float4 egr = ((const float4*)eGrT)[res];
        float f = __expf(Mt[tk + s] + Mt[tl + s + k] - Mt[offML + s]);
        float sub = dk0.x * dlh.x * egl.x + dk0.y * dlh.y * egl.y
                  + dk0.z * dlh.z * egl.z + dk0.w * dlh.w * egl.w
                  + dl0.x * dkh.x * egr.x + dl0.y * dkh.y * egr.y
                  + dl0.z * dkh.z * egr.z + dl0.w * dkh.w * egr.w;
        atomicAdd(&MIDacc[rem], f * sub);
      }
    }
    __syncthreads();

    // ---- phase 3: merge mids into D (res<4 columns)
    if (L >= 4) {
      for (int o = tid; o < 4 * S; o += 1024) {
        int s = o >> 2;
        float nv = D[offL + s * 36 + (o & 3)] + MIDacc[o];
        D[offL + s * 36 + (o & 3)] = nv;
        atomicMax(&candb[par][s], __float_as_uint(nv));
      }
    }
    __syncthreads();
  }

  int wid = tid >> 6, lane = tid & 63;
  if (wid == 0) {
    int off32 = 36 * ((31 * 34) >> 1);
    float v = (lane < 36) ? D[off32 + lane] * __expf(root36[lane]) : 0.f;
#pragma unroll
    for (int w = 32; w > 0; w >>= 1) v += __shfl_xor(v, w);
    if (lane == 0) out[b] = -(Mt[527] + __logf(v));
  }
}

// ---------------------------------------------------------------------------
extern "C" void kernel_launch(void* const* d_in, const int* in_sizes, int n_in,
                              void* d_out, int out_size, void* d_ws, size_t ws_size,
                              hipStream_t stream) {
  const int*   x       = (const int*)d_in[0];
  const int*   lf_t    = (const int*)d_in[1];
  const int*   rf_t    = (const int*)d_in[2];
  const float* root_W  = (const float*)d_in[3];
  const float* root_b  = (const float*)d_in[4];
  const float* rule_W  = (const float*)d_in[5];
  const float* rule_b  = (const float*)d_in[6];
  const float* nt_emb  = (const float*)d_in[7];
  const float* sW1     = (const float*)d_in[8];
  const float* sb1     = (const float*)d_in[9];
  const float* r1W1    = (const float*)d_in[10];
  const float* r1b1    = (const float*)d_in[11];
  const float* r1W2    = (const float*)d_in[12];
  const float* r1b2    = (const float*)d_in[13];
  const float* r2W1    = (const float*)d_in[14];
  const float* r2b1    = (const float*)d_in[15];
  const float* r2W2    = (const float*)d_in[16];
  const float* r2b2    = (const float*)d_in[17];
  const float* sW2     = (const float*)d_in[18];
  const float* sb2     = (const float*)d_in[19];
  const float* vocab_W = (const float*)d_in[20];
  const float* vocab_b = (const float*)d_in[21];
  float* outp = (float*)d_out;

  float* ws = (float*)d_ws;
  float* split0 = ws;                         // 2596
  float* split1 = ws + 2596;                  // 2596
  float* Gl     = ws + 5192;                  // 1296
  float* Gr     = ws + 6488;                  // 1296
  float* root36 = ws + 7784;                  // 64 (pad)
  float* lseacc = ws + 7848;                  // 2596 -> pad to 13040
  float* beta1  = ws + 13040;                 // 2658304 -> end 2671344
  float* elF    = ws + 2671344;               // 1024*1296 = 1327104 -> end 3998448
  float* erF    = ws + 3998448;               // 1327104 -> end 5325552
  // Wt (bf16 GEMM fragments, 4.1MB) overlays elF: consumed by k_lse_mfma
  // BEFORE k_edge writes elF (same stream => safe).
  uint4* Wt = (uint4*)(ws + 2671344);         // 256000 uint4

  k_mlp<<<649, 256, 0, stream>>>(nt_emb, sW1, sb1, r1W1, r1b1, r1W2, r1b2,
                                 r2W1, r2b1, r2W2, r2b2, sW2, sb2, split0, split1);
  k_prelim<<<1, 256, 0, stream>>>(rule_W, rule_b, root_W, root_b, split0, Gl, Gr, root36);
  k_cvt_w<<<1000, 256, 0, stream>>>(vocab_W, Wt);
  hipMemsetAsync(lseacc, 0, CT * sizeof(float), stream);
  k_lse_mfma<<<dim3(8, 41), 256, 0, stream>>>(nt_emb, Wt, vocab_b, lseacc);
  k_beta1<<<163, 256, 0, stream>>>(nt_emb, vocab_W, vocab_b, x, lseacc, split1, beta1);
  k_edge<<<1024, 256, 0, stream>>>(beta1, lf_t, rf_t, Gl, Gr, elF, erF);
  k_cky<<<32, 1024, 0, stream>>>(beta1, elF, erF, Gl, Gr, root36, outp);
}

// Round 6
// 228.441 us; speedup vs baseline: 3.3933x; 1.1562x over previous
//
#include <hip/hip_runtime.h>
#include <hip/hip_bf16.h>
#include <math.h>

#define CT 2596      // total functor count C
#define NF36 36
#define BB 32        // batch
#define NN 32        // seq len
#define VV 32000
#define DD 64
#define NEGF -1e9f
#define NVT 2000     // V tiles of 16

typedef __attribute__((ext_vector_type(8))) short bf16x8;
typedef __attribute__((ext_vector_type(4))) float f32x4;

// bf16 helpers
__device__ __forceinline__ uint32_t f2bf_bits(float x) {
  union { float f; uint32_t u; } v; v.f = x;
  return (v.u + 0x7FFFu + ((v.u >> 16) & 1u)) >> 16;   // RNE
}
__device__ __forceinline__ float bflo(uint32_t u) {
  union { uint32_t u; float f; } v; v.u = u << 16; return v.f;
}
__device__ __forceinline__ float bfhi(uint32_t u) {
  union { uint32_t u; float f; } v; v.u = u & 0xFFFF0000u; return v.f;
}

// ---------------------------------------------------------------------------
// K1: MLP over all C rows -> split0[c], split1[c]
__global__ __launch_bounds__(256) void k_mlp(
    const float* __restrict__ nt_emb,
    const float* __restrict__ sW1, const float* __restrict__ sb1,
    const float* __restrict__ r1W1, const float* __restrict__ r1b1,
    const float* __restrict__ r1W2, const float* __restrict__ r1b2,
    const float* __restrict__ r2W1, const float* __restrict__ r2b1,
    const float* __restrict__ r2W2, const float* __restrict__ r2b2,
    const float* __restrict__ sW2, const float* __restrict__ sb2,
    float* __restrict__ split0, float* __restrict__ split1) {
  int tid = threadIdx.x;
  int rl = tid >> 6, j = tid & 63;
  int c = blockIdx.x * 4 + rl;
  __shared__ float hs[4][64], ts[4][64];

  ts[rl][j] = nt_emb[(size_t)c * 64 + j];
  __syncthreads();
  float a = sb1[j];
  for (int i = 0; i < 64; i++) a += ts[rl][i] * sW1[i * 64 + j];
  __syncthreads();
  hs[rl][j] = a;
  __syncthreads();
  float u = r1b1[j];
  for (int i = 0; i < 64; i++) u += hs[rl][i] * r1W1[i * 64 + j];
  u = fmaxf(u, 0.f);
  ts[rl][j] = u;
  __syncthreads();
  float w = r1b2[j];
  for (int i = 0; i < 64; i++) w += ts[rl][i] * r1W2[i * 64 + j];
  w = fmaxf(w, 0.f) + hs[rl][j];
  __syncthreads();
  hs[rl][j] = w;
  __syncthreads();
  u = r2b1[j];
  for (int i = 0; i < 64; i++) u += hs[rl][i] * r2W1[i * 64 + j];
  u = fmaxf(u, 0.f);
  ts[rl][j] = u;
  __syncthreads();
  w = r2b2[j];
  for (int i = 0; i < 64; i++) w += ts[rl][i] * r2W2[i * 64 + j];
  w = fmaxf(w, 0.f) + hs[rl][j];
  __syncthreads();
  hs[rl][j] = w;
  __syncthreads();
  if (j < 2) {
    float o = sb2[j];
    for (int i = 0; i < 64; i++) o += hs[rl][i] * sW2[i * 2 + j];
    ts[rl][j] = o;
  }
  __syncthreads();
  if (j < 2) {
    float o0 = ts[rl][0], o1 = ts[rl][1];
    float mx = fmaxf(o0, o1);
    float l = mx + __logf(__expf(o0 - mx) + __expf(o1 - mx));
    if (j == 0) split0[c] = o0 - l;
    else        split1[c] = o1 - l;
  }
}

// ---------------------------------------------------------------------------
// K2: rule log_softmax + root scores + G tables (needs split0); zeroes lseacc
__global__ __launch_bounds__(256) void k_prelim(
    const float* __restrict__ rule_W, const float* __restrict__ rule_b,
    const float* __restrict__ root_W, const float* __restrict__ root_b,
    const float* __restrict__ split0,
    float* __restrict__ Gl, float* __restrict__ Gr, float* __restrict__ root36,
    float* __restrict__ lseacc) {
  __shared__ float rs[36 * 72];
  __shared__ float lse4s;
  int tid = threadIdx.x;
  for (int i = tid; i < CT; i += 256) lseacc[i] = 0.f;
  if (tid < 36) {
    float mx = -1e30f;
    for (int q = 0; q < 72; q++) mx = fmaxf(mx, rule_W[tid * 72 + q] + rule_b[q]);
    float ss = 0.f;
    for (int q = 0; q < 72; q++) ss += __expf(rule_W[tid * 72 + q] + rule_b[q] - mx);
    float l = mx + __logf(ss);
    for (int q = 0; q < 72; q++) rs[tid * 72 + q] = rule_W[tid * 72 + q] + rule_b[q] - l;
  }
  if (tid == 0) {
    float mx = -1e30f;
    for (int i = 0; i < 4; i++) mx = fmaxf(mx, root_W[i] + root_b[i]);
    float ss = 0.f;
    for (int i = 0; i < 4; i++) ss += __expf(root_W[i] + root_b[i] - mx);
    lse4s = mx + __logf(ss);
  }
  __syncthreads();
  if (tid < 36)
    root36[tid] = ((tid < 4) ? 0.f : NEGF) + root_W[tid] + root_b[tid] - lse4s;
  for (int i = tid; i < 1296; i += 256) {
    int arg = i / 36, res = i - arg * 36;
    float s0 = split0[res];
    Gl[i] = rs[res * 72 + arg] + s0;
    Gr[i] = rs[res * 72 + 36 + arg] + s0;
  }
}

// ---------------------------------------------------------------------------
// K3a: repack vocab_W into bf16 MFMA B-fragments.
__global__ __launch_bounds__(256) void k_cvt_w(
    const float* __restrict__ vocab_W, uint4* __restrict__ Wt) {
  int g = blockIdx.x * 256 + threadIdx.x;
  if (g >= NVT * 128) return;
  int l = g & 63;
  int f = (g >> 6) & 1;
  int vt = g >> 7;
  int v = vt * 16 + (l & 15);
  int kb = f * 32 + 8 * (l >> 4);
  uint32_t d[4];
#pragma unroll
  for (int p = 0; p < 4; p++) {
    float a = vocab_W[(size_t)(kb + 2 * p) * VV + v];
    float b = vocab_W[(size_t)(kb + 2 * p + 1) * VV + v];
    d[p] = f2bf_bits(a) | (f2bf_bits(b) << 16);
  }
  uint4 o; o.x = d[0]; o.y = d[1]; o.z = d[2]; o.w = d[3];
  Wt[g] = o;
}

// ---------------------------------------------------------------------------
// K3a': gather the 1024 token columns into bf16 B-fragments (done once).
// Bt[t*128 + kf*64 + l]: tile t (tokens t*16..t*16+15), k = kf*32+8*(l>>4)+{0..7}
__global__ __launch_bounds__(256) void k_gather_tok(
    const float* __restrict__ vocab_W, const float* __restrict__ vocab_b,
    const int* __restrict__ x, uint4* __restrict__ Bt, float* __restrict__ vbt) {
  int g = blockIdx.x * 256 + threadIdx.x;
  if (g >= 8192) return;
  int l = g & 63, kf = (g >> 6) & 1, t = g >> 7;
  int j = t * 16 + (l & 15);
  int tok = x[j];
  int kb = kf * 32 + 8 * (l >> 4);
  uint32_t d[4];
#pragma unroll
  for (int p = 0; p < 4; p++) {
    float a = vocab_W[(size_t)(kb + 2 * p) * VV + tok];
    float b = vocab_W[(size_t)(kb + 2 * p + 1) * VV + tok];
    d[p] = f2bf_bits(a) | (f2bf_bits(b) << 16);
  }
  uint4 o; o.x = d[0]; o.y = d[1]; o.z = d[2]; o.w = d[3];
  Bt[g] = o;
  if (g < 1024) vbt[g] = vocab_b[x[g]];
}

// ---------------------------------------------------------------------------
// K3b: MFMA GEMM + fused exp-sum over V. Block = 4 waves, owns 128 C-rows.
// grid = (25 v-slices of 80 tiles, 21 c-blocks).
__global__ __launch_bounds__(256) void k_lse_mfma(
    const float* __restrict__ nt_emb, const uint4* __restrict__ Wt,
    const float* __restrict__ vocab_b, float* __restrict__ lseacc) {
  int tid = threadIdx.x;
  int w = tid >> 6, l = tid & 63;
  int c0 = blockIdx.y * 128;
  int lrow = l & 15, lgrp = l >> 4;

  bf16x8 A[8][2];
#pragma unroll
  for (int ct = 0; ct < 8; ct++) {
    int row = c0 + ct * 16 + lrow;
#pragma unroll
    for (int kf = 0; kf < 2; kf++) {
      bf16x8 fr;
      if (row < CT) {
        const float4* src = (const float4*)(nt_emb + (size_t)row * 64 + kf * 32 + lgrp * 8);
        float4 s0 = src[0], s1 = src[1];
        fr[0] = (short)f2bf_bits(s0.x); fr[1] = (short)f2bf_bits(s0.y);
        fr[2] = (short)f2bf_bits(s0.z); fr[3] = (short)f2bf_bits(s0.w);
        fr[4] = (short)f2bf_bits(s1.x); fr[5] = (short)f2bf_bits(s1.y);
        fr[6] = (short)f2bf_bits(s1.z); fr[7] = (short)f2bf_bits(s1.w);
      } else {
#pragma unroll
        for (int e = 0; e < 8; e++) fr[e] = 0;
      }
      A[ct][kf] = fr;
    }
  }

  float sums[8][4];
#pragma unroll
  for (int ct = 0; ct < 8; ct++)
#pragma unroll
    for (int i = 0; i < 4; i++) sums[ct][i] = 0.f;

  int t0 = blockIdx.x * 80;
  for (int t = t0 + w; t < t0 + 80; t += 4) {
    union { uint4 u; bf16x8 h; } b0, b1;
    b0.u = Wt[(size_t)(t * 2) * 64 + l];
    b1.u = Wt[(size_t)(t * 2 + 1) * 64 + l];
    float vb = vocab_b[t * 16 + lrow];
#pragma unroll
    for (int ct = 0; ct < 8; ct++) {
      f32x4 acc = {0.f, 0.f, 0.f, 0.f};
      acc = __builtin_amdgcn_mfma_f32_16x16x32_bf16(A[ct][0], b0.h, acc, 0, 0, 0);
      acc = __builtin_amdgcn_mfma_f32_16x16x32_bf16(A[ct][1], b1.h, acc, 0, 0, 0);
#pragma unroll
      for (int i = 0; i < 4; i++) sums[ct][i] += __expf(acc[i] + vb);
    }
  }

#pragma unroll
  for (int ct = 0; ct < 8; ct++)
#pragma unroll
    for (int i = 0; i < 4; i++) {
      float v = sums[ct][i];
      v += __shfl_xor(v, 1);
      v += __shfl_xor(v, 2);
      v += __shfl_xor(v, 4);
      v += __shfl_xor(v, 8);
      sums[ct][i] = v;
    }
  if (lrow == 0) {
#pragma unroll
    for (int ct = 0; ct < 8; ct++)
#pragma unroll
      for (int i = 0; i < 4; i++) {
        int row = c0 + ct * 16 + lgrp * 4 + i;
        if (row < CT) atomicAdd(&lseacc[row], sums[ct][i]);
      }
  }
}

// ---------------------------------------------------------------------------
// K5: beta1 via MFMA against the gathered token fragments.
// beta1[(n*32+b)*CT + c] = logit(c, x[b,n]) + vb - log(lseacc[c]) + split1[c]
__global__ __launch_bounds__(256) void k_beta1_mfma(
    const float* __restrict__ nt_emb, const uint4* __restrict__ Bt,
    const float* __restrict__ vbt, const float* __restrict__ lseacc,
    const float* __restrict__ split1, float* __restrict__ beta1) {
  int tid = threadIdx.x;
  int w = tid >> 6, l = tid & 63;
  int c0 = blockIdx.x * 64;
  int lrow = l & 15, lgrp = l >> 4;
  __shared__ float addS[64];
  if (tid < 64) {
    int row = c0 + tid;
    addS[tid] = (row < CT) ? (split1[row] - __logf(lseacc[row])) : 0.f;
  }

  bf16x8 A[4][2];
#pragma unroll
  for (int ct = 0; ct < 4; ct++) {
    int row = c0 + ct * 16 + lrow;
#pragma unroll
    for (int kf = 0; kf < 2; kf++) {
      bf16x8 fr;
      if (row < CT) {
        const float4* src = (const float4*)(nt_emb + (size_t)row * 64 + kf * 32 + lgrp * 8);
        float4 s0 = src[0], s1 = src[1];
        fr[0] = (short)f2bf_bits(s0.x); fr[1] = (short)f2bf_bits(s0.y);
        fr[2] = (short)f2bf_bits(s0.z); fr[3] = (short)f2bf_bits(s0.w);
        fr[4] = (short)f2bf_bits(s1.x); fr[5] = (short)f2bf_bits(s1.y);
        fr[6] = (short)f2bf_bits(s1.z); fr[7] = (short)f2bf_bits(s1.w);
      } else {
#pragma unroll
        for (int e = 0; e < 8; e++) fr[e] = 0;
      }
      A[ct][kf] = fr;
    }
  }
  __syncthreads();
  float addv[4][4];
#pragma unroll
  for (int ct = 0; ct < 4; ct++)
#pragma unroll
    for (int i = 0; i < 4; i++) addv[ct][i] = addS[ct * 16 + lgrp * 4 + i];

  for (int t = w; t < 64; t += 4) {
    union { uint4 u; bf16x8 h; } b0, b1;
    b0.u = Bt[t * 128 + l];
    b1.u = Bt[t * 128 + 64 + l];
    int j = t * 16 + lrow;
    float vb = vbt[j];
    int jc = (j & 31) * 32 + (j >> 5);
    float* outb = beta1 + (size_t)jc * CT;
#pragma unroll
    for (int ct = 0; ct < 4; ct++) {
      f32x4 acc = {0.f, 0.f, 0.f, 0.f};
      acc = __builtin_amdgcn_mfma_f32_16x16x32_bf16(A[ct][0], b0.h, acc, 0, 0, 0);
      acc = __builtin_amdgcn_mfma_f32_16x16x32_bf16(A[ct][1], b1.h, acc, 0, 0, 0);
      int r0 = c0 + ct * 16 + lgrp * 4;
      if (r0 + 3 < CT) {
        float4 o;
        o.x = acc[0] + vb + addv[ct][0];
        o.y = acc[1] + vb + addv[ct][1];
        o.z = acc[2] + vb + addv[ct][2];
        o.w = acc[3] + vb + addv[ct][3];
        *(float4*)(outb + r0) = o;
      } else {
        for (int i = 0; i < 4; i++)
          if (r0 + i < CT) outb[r0 + i] = acc[i] + vb + addv[ct][i];
      }
    }
  }
}

// ---------------------------------------------------------------------------
// K6: EXP-space edge tables, bf16-pair packed, layout [sb][res][20 u32 words].
// word p of row (sb,res) packs args (2p, 2p+1); args>=36 are 0.
__global__ __launch_bounds__(256) void k_edge(
    const float* __restrict__ beta1, const int* __restrict__ lf_t,
    const int* __restrict__ rf_t, const float* __restrict__ Gl,
    const float* __restrict__ Gr,
    uint32_t* __restrict__ elB, uint32_t* __restrict__ erB) {
  int sb = blockIdx.x;
  const float* brow = beta1 + (size_t)sb * CT;
  size_t ob = (size_t)sb * 720;
  for (int wd = threadIdx.x; wd < 720; wd += 256) {
    int res = wd / 20, p = wd - res * 20;
    int a0 = 2 * p, a1 = 2 * p + 1;
    uint32_t l0 = 0, l1 = 0, r0 = 0, r1 = 0;
    if (a0 < 36) {
      int i0 = a0 * 36 + res;
      l0 = f2bf_bits(__expf(brow[lf_t[i0]] + Gr[i0]));
      r0 = f2bf_bits(__expf(brow[rf_t[i0]] + Gl[i0]));
    }
    if (a1 < 36) {
      int i1 = a1 * 36 + res;
      l1 = f2bf_bits(__expf(brow[lf_t[i1]] + Gr[i1]));
      r1 = f2bf_bits(__expf(brow[rf_t[i1]] + Gl[i1]));
    }
    elB[ob + wd] = l0 | (l1 << 16);
    erB[ob + wd] = r0 | (r1 << 16);
  }
}

// ---------------------------------------------------------------------------
// K7: CKY inside pass, EXP-space, bf16 edge tables. One block per batch elem.
__global__ __launch_bounds__(1024, 4) void k_cky(
    const float* __restrict__ beta1, const uint32_t* __restrict__ elB,
    const uint32_t* __restrict__ erB, const float* __restrict__ Gl,
    const float* __restrict__ Gr, const float* __restrict__ root36,
    float* __restrict__ out) {
  __shared__ __align__(16) float D[19008];
  __shared__ float Mt[528];
  __shared__ __align__(16) float PA[1280], PB[1280];      // stride 40, padded
  __shared__ __align__(16) float Ec1lT[512], Ec1rT[512];  // [s][res][a]
  __shared__ __align__(16) float eGlT[16], eGrT[16];      // [res][a]
  __shared__ unsigned int candb[2][33];
  __shared__ float MIDacc[128];

  int b = blockIdx.x, tid = threadIdx.x;

  if (tid < 66) candb[tid / 33][tid % 33] = 0u;
  if (tid < 32) Mt[tid] = 0.f;
  if (tid < 16) {
    int res = tid >> 2, a = tid & 3;
    eGlT[tid] = __expf(Gl[a * 36 + res]);
    eGrT[tid] = __expf(Gr[a * 36 + res]);
  }
  for (int i = tid; i < 1280; i += 1024) { PA[i] = 0.f; PB[i] = 0.f; }
  __syncthreads();
  for (int i = tid; i < 32 * 36; i += 1024) {
    int s = i / 36;
    float v = __expf(beta1[(size_t)(s * 32 + b) * CT + (i - s * 36)]);
    D[i] = v;
    atomicMax(&candb[1][s], __float_as_uint(v));
  }
  __syncthreads();
  for (int i = tid; i < 512; i += 1024) {
    int s = i >> 4, rr = (i >> 2) & 3, a = i & 3;
    float d1 = D[s * 36 + a];
    Ec1lT[i] = d1 * eGlT[rr * 4 + a];
    Ec1rT[i] = d1 * eGrT[rr * 4 + a];
  }
  __syncthreads();

  for (int L = 2; L <= 32; L++) {
    int S = 33 - L;
    int offL  = 36 * (((L - 1) * (66 - L)) >> 1);
    int offP  = 36 * (((L - 2) * (67 - L)) >> 1);
    int offML = ((L - 1) * (66 - L)) >> 1;
    int offMP = ((L - 2) * (67 - L)) >> 1;
    int par = L & 1, parP = par ^ 1;

    // ---- phase A: scale prev level into PA/PB; zero candb[par], MIDacc
    if (tid < 33) candb[par][tid] = 0u;
    if (tid >= 64 && tid < 192) MIDacc[tid - 64] = 0.f;
    int totA = S * 36;
    for (int o = tid; o < totA; o += 1024) {
      int s = o / 36, j = o - s * 36;
      float MtA = Mt[offMP + s], MtB = Mt[offMP + s + 1];
      float cA = MtA + __logf(fmaxf(__uint_as_float(candb[parP][s]), 1e-37f));
      float cB = MtB + __logf(fmaxf(__uint_as_float(candb[parP][s + 1]), 1e-37f));
      float Mn = fmaxf(cA, cB);
      PA[s * 40 + j] = D[offP + s * 36 + j] * __expf(MtA - Mn);
      PB[s * 40 + j] = D[offP + (s + 1) * 36 + j] * __expf(MtB - Mn);
      if (j == 0) Mt[offML + s] = Mn;
    }
    __syncthreads();

    // ---- phase 2: mains + parallel mids
    int tot = S * 36;
    int nmid = (L >= 4) ? 4 * S * (L - 3) : 0;
    int W = tot + nmid;
    for (int o = tid; o < W; o += 1024) {
      if (o < tot) {
        int s = o / 36, res = o - s * 36;
        const uint4* el4 = (const uint4*)(elB + (size_t)(s * 32 + b) * 720 + res * 20);
        const uint4* er4 = (const uint4*)(erB + (size_t)((s + L - 1) * 32 + b) * 720 + res * 20);
        const float4* pB4 = (const float4*)(PB + s * 40);
        const float4* pA4 = (const float4*)(PA + s * 40);
        float a0 = 0.f, a1 = 0.f, a2 = 0.f, a3 = 0.f;
#pragma unroll
        for (int q = 0; q < 5; q++) {
          uint4 u = el4[q];
          float4 p0 = pB4[2 * q], p1 = pB4[2 * q + 1];
          a0 = fmaf(bflo(u.x), p0.x, a0); a1 = fmaf(bfhi(u.x), p0.y, a1);
          a2 = fmaf(bflo(u.y), p0.z, a2); a3 = fmaf(bfhi(u.y), p0.w, a3);
          a0 = fmaf(bflo(u.z), p1.x, a0); a1 = fmaf(bfhi(u.z), p1.y, a1);
          a2 = fmaf(bflo(u.w), p1.z, a2); a3 = fmaf(bfhi(u.w), p1.w, a3);
          uint4 v = er4[q];
          float4 q0 = pA4[2 * q], q1 = pA4[2 * q + 1];
          a0 = fmaf(bflo(v.x), q0.x, a0); a1 = fmaf(bfhi(v.x), q0.y, a1);
          a2 = fmaf(bflo(v.y), q0.z, a2); a3 = fmaf(bfhi(v.y), q0.w, a3);
          a0 = fmaf(bflo(v.z), q1.x, a0); a1 = fmaf(bfhi(v.z), q1.y, a1);
          a2 = fmaf(bflo(v.w), q1.z, a2); a3 = fmaf(bfhi(v.w), q1.w, a3);
        }
        if (res < 4 && L >= 3) {
          const float4* ecl = (const float4*)(Ec1lT + s * 16 + res * 4);
          const float4* ecr = (const float4*)(Ec1rT + (s + L - 1) * 16 + res * 4);
          float4 e0 = ecl[0], pb = pB4[5 + res];
          float4 e1 = ecr[0], pa = pA4[1 + res];
          a0 = fmaf(e0.x, pb.x, a0); a1 = fmaf(e0.y, pb.y, a1);
          a2 = fmaf(e0.z, pb.z, a2); a3 = fmaf(e0.w, pb.w, a3);
          a0 = fmaf(e1.x, pa.x, a0); a1 = fmaf(e1.y, pa.y, a1);
          a2 = fmaf(e1.z, pa.z, a2); a3 = fmaf(e1.w, pa.w, a3);
        }
        float val = (a0 + a1) + (a2 + a3);
        D[offL + o] = val;
        atomicMax(&candb[par][s], __float_as_uint(val));
      } else {
        int o2 = o - tot;
        int kidx = o2 / (4 * S);
        int rem = o2 - kidx * 4 * S;
        int s = rem >> 2, res = rem & 3;
        int k = kidx + 2;
        int lk = L - k;
        int tk = ((k - 1) * (66 - k)) >> 1;
        int tl = ((lk - 1) * (66 - lk)) >> 1;
        const float4* Dk4 = (const float4*)(D + 36 * tk + s * 36);
        const float4* Dl4 = (const float4*)(D + 36 * tl + (s + k) * 36);
        float4 dk0 = Dk4[0], dkh = Dk4[1 + res];
        float4 dl0 = Dl4[0], dlh = Dl4[5 + res];
        float4 egl = ((const float4*)eGlT)[res];
        float4 egr = ((const float4*)eGrT)[res];
        float f = __expf(Mt[tk + s] + Mt[tl + s + k] - Mt[offML + s]);
        float sub = dk0.x * dlh.x * egl.x + dk0.y * dlh.y * egl.y
                  + dk0.z * dlh.z * egl.z + dk0.w * dlh.w * egl.w
                  + dl0.x * dkh.x * egr.x + dl0.y * dkh.y * egr.y
                  + dl0.z * dkh.z * egr.z + dl0.w * dkh.w * egr.w;
        atomicAdd(&MIDacc[rem], f * sub);
      }
    }
    __syncthreads();

    // ---- phase 3: merge mids into D (res<4 columns)
    if (L >= 4) {
      for (int o = tid; o < 4 * S; o += 1024) {
        int s = o >> 2;
        float nv = D[offL + s * 36 + (o & 3)] + MIDacc[o];
        D[offL + s * 36 + (o & 3)] = nv;
        atomicMax(&candb[par][s], __float_as_uint(nv));
      }
    }
    __syncthreads();
  }

  int wid = tid >> 6, lane = tid & 63;
  if (wid == 0) {
    int off32 = 36 * ((31 * 34) >> 1);
    float v = (lane < 36) ? D[off32 + lane] * __expf(root36[lane]) : 0.f;
#pragma unroll
    for (int w = 32; w > 0; w >>= 1) v += __shfl_xor(v, w);
    if (lane == 0) out[b] = -(Mt[527] + __logf(v));
  }
}

// ---------------------------------------------------------------------------
extern "C" void kernel_launch(void* const* d_in, const int* in_sizes, int n_in,
                              void* d_out, int out_size, void* d_ws, size_t ws_size,
                              hipStream_t stream) {
  const int*   x       = (const int*)d_in[0];
  const int*   lf_t    = (const int*)d_in[1];
  const int*   rf_t    = (const int*)d_in[2];
  const float* root_W  = (const float*)d_in[3];
  const float* root_b  = (const float*)d_in[4];
  const float* rule_W  = (const float*)d_in[5];
  const float* rule_b  = (const float*)d_in[6];
  const float* nt_emb  = (const float*)d_in[7];
  const float* sW1     = (const float*)d_in[8];
  const float* sb1     = (const float*)d_in[9];
  const float* r1W1    = (const float*)d_in[10];
  const float* r1b1    = (const float*)d_in[11];
  const float* r1W2    = (const float*)d_in[12];
  const float* r1b2    = (const float*)d_in[13];
  const float* r2W1    = (const float*)d_in[14];
  const float* r2b1    = (const float*)d_in[15];
  const float* r2W2    = (const float*)d_in[16];
  const float* r2b2    = (const float*)d_in[17];
  const float* sW2     = (const float*)d_in[18];
  const float* sb2     = (const float*)d_in[19];
  const float* vocab_W = (const float*)d_in[20];
  const float* vocab_b = (const float*)d_in[21];
  float* outp = (float*)d_out;

  float* ws = (float*)d_ws;
  float* split0 = ws;                         // 2596
  float* split1 = ws + 2596;                  // 2596
  float* Gl     = ws + 5192;                  // 1296
  float* Gr     = ws + 6488;                  // 1296
  float* root36 = ws + 7784;                  // 64
  float* lseacc = ws + 7848;                  // 2596 (pad to 2600)
  float* vbt    = ws + 10448;                 // 1024
  float* beta1  = ws + 11472;                 // 2658304 -> end 2669776
  uint32_t* elB = (uint32_t*)(ws + 2669776);  // 1024*720 = 737280 -> end 3407056
  uint32_t* erB = (uint32_t*)(ws + 3407056);  // 737280 -> end 4144336
  // Wt overlays elB/erB region: consumed by k_lse_mfma BEFORE k_edge writes.
  uint4* Wt     = (uint4*)(ws + 2669776);     // 256000 uint4 = 1024000 floats
  uint4* Bt     = (uint4*)(ws + 4144336);     // 8192 uint4 -> end 4177104

  k_mlp<<<649, 256, 0, stream>>>(nt_emb, sW1, sb1, r1W1, r1b1, r1W2, r1b2,
                                 r2W1, r2b1, r2W2, r2b2, sW2, sb2, split0, split1);
  k_prelim<<<1, 256, 0, stream>>>(rule_W, rule_b, root_W, root_b, split0,
                                  Gl, Gr, root36, lseacc);
  k_cvt_w<<<1000, 256, 0, stream>>>(vocab_W, Wt);
  k_gather_tok<<<32, 256, 0, stream>>>(vocab_W, vocab_b, x, Bt, vbt);
  k_lse_mfma<<<dim3(25, 21), 256, 0, stream>>>(nt_emb, Wt, vocab_b, lseacc);
  k_beta1_mfma<<<41, 256, 0, stream>>>(nt_emb, Bt, vbt, lseacc, split1, beta1);
  k_edge<<<1024, 256, 0, stream>>>(beta1, lf_t, rf_t, Gl, Gr, elB, erB);
  k_cky<<<32, 1024, 0, stream>>>(beta1, elB, erB, Gl, Gr, root36, outp);
}